// Round 13
// baseline (323.682 us; speedup 1.0000x reference)
//
#include <hip/hip_runtime.h>
#include <hip/hip_bf16.h>

#define DIMD 384
#define SEQL 4096
#define NBATCH 8
#define NTOK (NBATCH*SEQL)

typedef float f32x4 __attribute__((ext_vector_type(4)));
typedef short s16x8 __attribute__((ext_vector_type(8)));
typedef unsigned short u16;
typedef __hip_bfloat16 bf16;

__device__ __forceinline__ float sigf(float x){ return 1.f/(1.f+__expf(-x)); }

// async global->LDS, 16B per lane. LDS dest must be wave-uniform base + lane*16.
typedef __attribute__((address_space(3))) void lds_void;
typedef const __attribute__((address_space(1))) void glb_void;
__device__ __forceinline__ void gl_lds16(const void* g, void* l) {
  __builtin_amdgcn_global_load_lds((glb_void*)g, (lds_void*)l, 16, 0, 0);
}

// ---------------- workspace layout (bytes) ----------------
#define OFF_LAM   0ul
#define OFF_WQ    4096ul                       // bf16 [1536][384]
#define OFF_CW    (OFF_WQ + 1179648ul)         // bf16 [384][448]
#define OFF_W1T   (OFF_CW + 344064ul)          // bf16 [768][384]
#define OFF_W2T   (OFF_W1T + 589824ul)         // bf16 [384][768]
#define OFF_XC    4194304ul                    // bf16 [32768][384]
#define OFF_Q     (OFF_XC + 25165824ul)        // bf16 [32768][384]
#define OFF_U     (OFF_XC + 50331648ul)        // bf16 [32768][384]
#define OFF_AI    OFF_U                        // bf16 [32768][768] (reuse after u dead)
#define OFF_H     (OFF_U + 50331648ul)         // bf16 [32768][384]
// total = 130,023,424 bytes

// ---------------- prep: weight transposes to [n][k] bf16 ----------------
__global__ void k_prep_w(const float* __restrict__ qw, const float* __restrict__ kw,
                         const float* __restrict__ vw, const float* __restrict__ gw,
                         const float* __restrict__ cw, const float* __restrict__ w1,
                         const float* __restrict__ w2,
                         bf16* __restrict__ wqt, bf16* __restrict__ cwt,
                         bf16* __restrict__ w1t, bf16* __restrict__ w2t) {
  const int total = 589824 + 172032 + 294912 + 294912;
  for (int j = blockIdx.x*blockDim.x + threadIdx.x; j < total; j += gridDim.x*blockDim.x) {
    if (j < 589824) {
      int n = j / 384, k = j % 384;
      int mat = n / 384;
      int np = n % 384;                        // (384 not pow2 -> %, not &)
      const float* W = (mat==0)?qw:(mat==1)?kw:(mat==2)?vw:gw;
      wqt[(size_t)n*384 + k] = __float2bfloat16(W[(size_t)k*384 + np]);
    } else if (j < 589824 + 172032) {
      int jj = j - 589824;
      int o = jj / 448, k = jj % 448;
      int kap = k >> 6, i = k & 63;
      cwt[(size_t)o*448 + k] = __float2bfloat16(cw[((size_t)o*64 + i)*7 + kap]);
    } else if (j < 589824 + 172032 + 294912) {
      int jj = j - (589824 + 172032);
      int n = jj / 384, k = jj % 384;
      w1t[(size_t)n*384 + k] = __float2bfloat16(w1[(size_t)k*768 + n]);
    } else {
      int jj = j - (589824 + 172032 + 294912);
      int n = jj / 768, k = jj % 768;
      w2t[(size_t)n*768 + k] = __float2bfloat16(w2[(size_t)k*384 + n]);
    }
  }
}

__global__ void k_prep_lam(const float* __restrict__ decay, float* __restrict__ lam) {
  __shared__ float red[6];
  int t = threadIdx.x; // 384 threads
  float v = sigf(decay[t]);
  for (int off = 32; off; off >>= 1) v += __shfl_xor(v, off, 64);
  if ((t & 63) == 0) red[t >> 6] = v;
  __syncthreads();
  if (t == 0) {
    float s = 0.f;
    for (int i = 0; i < 6; ++i) s += red[i];
    lam[0] = s * (1.f/384.f);
  }
}

// ---------------- grouped conv (k=7, groups=6) + silu -> xc bf16 ----------------
__global__ __launch_bounds__(256) void k_conv(const float* __restrict__ x, const float* __restrict__ cb,
                                              const bf16* __restrict__ cwt, bf16* __restrict__ xc) {
  int id = blockIdx.x;             // 1536 = 8 b * 32 st * 6 g
  int g = id % 6, st = (id/6) & 31, b = id / 192;
  int s0 = st * 128;
  __shared__ u16 xls[134*72];
  __shared__ u16 wls[64*456];
  int tid = threadIdx.x;
  for (int r0 = 0; r0 < 144; r0 += 16) {
    int row = r0 + (tid >> 4);
    if (row < 134) {
      int col = (tid & 15) * 4;
      int s = s0 - 3 + row;
      float4 v = make_float4(0.f,0.f,0.f,0.f);
      if (s >= 0 && s < SEQL)
        v = *reinterpret_cast<const float4*>(x + ((size_t)(b*SEQL + s))*DIMD + g*64 + col);
      u16* dst = &xls[row*72 + col];
      bf16 t0 = __float2bfloat16(v.x); dst[0] = *reinterpret_cast<u16*>(&t0);
      bf16 t1 = __float2bfloat16(v.y); dst[1] = *reinterpret_cast<u16*>(&t1);
      bf16 t2 = __float2bfloat16(v.z); dst[2] = *reinterpret_cast<u16*>(&t2);
      bf16 t3 = __float2bfloat16(v.w); dst[3] = *reinterpret_cast<u16*>(&t3);
    }
  }
  for (int i0 = 0; i0 < 28672; i0 += 1024) {
    int i = i0 + tid*4;
    int o = i / 448, k = i % 448;
    *reinterpret_cast<uint2*>(&wls[o*456 + k]) =
      *reinterpret_cast<const uint2*>(cwt + ((size_t)(g*64 + o))*448 + k);
  }
  __syncthreads();
  int w = tid >> 6, l = tid & 63, l15 = l & 15, lh = l >> 4;
  f32x4 zz = {0.f,0.f,0.f,0.f};
  f32x4 acc[2][4];
  for (int i=0;i<2;++i) for (int jn=0;jn<4;++jn) acc[i][jn]=zz;
  for (int kap = 0; kap < 7; ++kap) {
#pragma unroll
    for (int ic = 0; ic < 2; ++ic) {
      s16x8 a0 = *reinterpret_cast<const s16x8*>(&xls[(w*32 +  0 + l15 + kap)*72 + ic*32 + lh*8]);
      s16x8 a1 = *reinterpret_cast<const s16x8*>(&xls[(w*32 + 16 + l15 + kap)*72 + ic*32 + lh*8]);
#pragma unroll
      for (int nf = 0; nf < 4; ++nf) {
        s16x8 bfr = *reinterpret_cast<const s16x8*>(&wls[(nf*16 + l15)*456 + kap*64 + ic*32 + lh*8]);
        acc[0][nf] = __builtin_amdgcn_mfma_f32_16x16x32_bf16(a0, bfr, acc[0][nf], 0,0,0);
        acc[1][nf] = __builtin_amdgcn_mfma_f32_16x16x32_bf16(a1, bfr, acc[1][nf], 0,0,0);
      }
    }
  }
#pragma unroll
  for (int nf = 0; nf < 4; ++nf) {
    int ch = g*64 + nf*16 + l15;
    float bias = cb[ch];
#pragma unroll
    for (int mf = 0; mf < 2; ++mf) {
#pragma unroll
      for (int r = 0; r < 4; ++r) {
        int m = w*32 + mf*16 + lh*4 + r;
        float v = acc[mf][nf][r] + bias;
        v = v * sigf(v);
        xc[((size_t)(b*SEQL + s0 + m))*DIMD + ch] = __float2bfloat16(v);
      }
    }
  }
}

// ---------------- fused QKVG GEMM (R13): wave-owns-ROWS, u in-register, no exchange ----------
// grid 3072 = 256 mt x 12 ct. Wave w owns rows [32w,32w+32) x ALL 4 matrices (32 cols c0..c0+32).
// A-reads 4x fewer (2 b128/kk); B-frags identical across waves (L1 broadcast); k,v,g for each
// (m,c) land in the same lane -> u computed in registers, exchange phase deleted.
__global__ __launch_bounds__(256) void k_qkvg(const bf16* __restrict__ xc, const bf16* __restrict__ wt,
    const float* __restrict__ qb, const float* __restrict__ kb,
    const float* __restrict__ vb, const float* __restrict__ gb,
    bf16* __restrict__ qout, bf16* __restrict__ uout) {
  int raw = blockIdx.x;                       // 3072
  int vv = (raw & 7)*384 + (raw >> 3);        // XCD swizzle
  int mt = vv / 12, ct = vv % 12;
  int m0 = mt*128, c0 = ct*32;
  __shared__ __align__(16) u16 als[16384];    // 32KB A-stage [128][128]
  int tid = threadIdx.x, w = tid >> 6, l = tid & 63, l15 = l & 15, lh = l >> 4;
  int wm = w*32;
  f32x4 zz = {0.f,0.f,0.f,0.f};
  f32x4 acc[2][8];                            // [mf][mat*2+nf]
#pragma unroll
  for (int i=0;i<2;++i)
#pragma unroll
    for (int j=0;j<8;++j) acc[i][j]=zz;
  const bf16* bbase = wt + ((size_t)(c0 + l15))*384 + lh*8;
  for (int kc = 0; kc < 3; ++kc) {
#pragma unroll
    for (int p = 0; p < 8; ++p) {
      int off16 = p*256 + tid;
      int row = off16 >> 4, slot = off16 & 15;
      int sslot = slot ^ (row & 7);
      gl_lds16(xc + ((size_t)(m0+row))*DIMD + kc*128 + sslot*8,
               (char*)als + off16*16);
    }
    __syncthreads();
#pragma unroll
    for (int kk = 0; kk < 4; ++kk) {
      int ko = kc*128 + kk*32;
      s16x8 bfr[8];
#pragma unroll
      for (int mb = 0; mb < 4; ++mb)
#pragma unroll
        for (int nf = 0; nf < 2; ++nf)
          bfr[mb*2+nf] = *reinterpret_cast<const s16x8*>(
              bbase + (size_t)(mb*384 + nf*16)*384 + ko);
#pragma unroll
      for (int mf = 0; mf < 2; ++mf) {
        s16x8 af = *reinterpret_cast<const s16x8*>(
            &als[(wm + mf*16 + l15)*128 + (((kk*4 + lh) ^ (l15 & 7))*8)]);
#pragma unroll
        for (int j = 0; j < 8; ++j)
          acc[mf][j] = __builtin_amdgcn_mfma_f32_16x16x32_bf16(af, bfr[j], acc[mf][j], 0,0,0);
      }
    }
    __syncthreads();
  }
  // epilogue: q + u fully in-register
  float qb0[2], kb0[2], vb0[2], gb0[2];
#pragma unroll
  for (int nf = 0; nf < 2; ++nf) {
    int c = c0 + nf*16 + l15;
    qb0[nf] = qb[c]; kb0[nf] = kb[c]; vb0[nf] = vb[c]; gb0[nf] = gb[c];
  }
#pragma unroll
  for (int mf = 0; mf < 2; ++mf) {
#pragma unroll
    for (int nf = 0; nf < 2; ++nf) {
#pragma unroll
      for (int r = 0; r < 4; ++r) {
        int m = m0 + wm + mf*16 + lh*4 + r;
        int c = c0 + nf*16 + l15;
        size_t idx = (size_t)m*DIMD + c;
        qout[idx] = __float2bfloat16(acc[mf][0+nf][r] + qb0[nf]);
        float kv = acc[mf][2+nf][r] + kb0[nf];
        float vv2 = acc[mf][4+nf][r] + vb0[nf];
        float gv = acc[mf][6+nf][r] + gb0[nf];
        uout[idx] = __float2bfloat16(vv2 * sigf(gv) * kv);
      }
    }
  }
}

// ---------------- decayed cumsum + q*diag + LN1 -> h bf16 (48KB LDS, 3 blocks/CU) -------------
__global__ __launch_bounds__(384) void k_scan(const bf16* __restrict__ u, const bf16* __restrict__ q,
    const float* __restrict__ lam_p, const float* __restrict__ l1g, const float* __restrict__ l1b,
    bf16* __restrict__ h) {
  int b = blockIdx.x >> 5, c = blockIdx.x & 31; // 8 x 32
  int d = threadIdx.x;                          // 384
  float lam = lam_p[0];
  __shared__ float ols[32*384];                 // 48 KB
  __shared__ float lgs[384], lbs[384];
  lgs[d] = l1g[d]; lbs[d] = l1b[d];
  int s0 = c*128;
  size_t base = ((size_t)b*SEQL)*DIMD + d;
  float carry = 0.f;
  int sstart = s0 - 64; if (sstart < 0) sstart = 0;
  for (int s = sstart; s < s0; s += 8) {
    float uv[8];
#pragma unroll
    for (int j = 0; j < 8; ++j) uv[j] = __bfloat162float(u[base + (size_t)(s+j)*DIMD]);
#pragma unroll
    for (int j = 0; j < 8; ++j) carry = carry*lam + uv[j];
  }
  int w = d >> 6, lane = d & 63;
  for (int p = 0; p < 4; ++p) {
    int sb = s0 + p*32;
    __syncthreads();
    for (int it0 = 0; it0 < 32; it0 += 8) {
      float uv[8], qv[8];
#pragma unroll
      for (int j = 0; j < 8; ++j) uv[j] = __bfloat162float(u[base + (size_t)(sb+it0+j)*DIMD]);
#pragma unroll
      for (int j = 0; j < 8; ++j) qv[j] = __bfloat162float(q[base + (size_t)(sb+it0+j)*DIMD]);
#pragma unroll
      for (int j = 0; j < 8; ++j) {
        carry = carry*lam + uv[j];
        ols[(it0+j)*384 + d] = carry * qv[j];
      }
    }
    __syncthreads();
    for (int t = w; t < 32; t += 6) {
      float vv[6]; float s1 = 0.f, s2 = 0.f;
#pragma unroll
      for (int j = 0; j < 6; ++j) {
        vv[j] = ols[t*384 + j*64 + lane];
        s1 += vv[j]; s2 += vv[j]*vv[j];
      }
      for (int off = 32; off; off >>= 1) { s1 += __shfl_xor(s1, off, 64); s2 += __shfl_xor(s2, off, 64); }
      float mean = s1 * (1.f/384.f);
      float var = s2 * (1.f/384.f) - mean*mean;
      float rs = rsqrtf(var + 1e-5f);
      size_t rowo = ((size_t)(b*SEQL + sb + t))*DIMD;
#pragma unroll
      for (int j = 0; j < 6; ++j) {
        int dd = j*64 + lane;
        h[rowo + dd] = __float2bfloat16((vv[j]-mean)*rs*lgs[dd] + lbs[dd]);
      }
    }
  }
}

// ---------------- MLP GEMM1 + silu -> ai bf16 (B reg-dbuf) ----------------
__global__ __launch_bounds__(256) void k_mlp1(const bf16* __restrict__ h, const bf16* __restrict__ w1t,
                                              const float* __restrict__ b1, bf16* __restrict__ ai) {
  int raw = blockIdx.x;                 // 1536
  int vv = (raw & 7)*192 + (raw >> 3);
  int mt = vv / 6, nt = vv % 6;
  int m0 = mt*128, n0 = nt*128;
  __shared__ __align__(16) u16 als[16384];
  int tid = threadIdx.x, w = tid >> 6, l = tid & 63, l15 = l & 15, lh = l >> 4;
  int wm = (w >> 1)*64, wn = (w & 1)*64;
  f32x4 zz = {0.f,0.f,0.f,0.f};
  f32x4 acc[4][4];
#pragma unroll
  for (int i=0;i<4;++i) for (int jn=0;jn<4;++jn) acc[i][jn]=zz;
  const bf16* bp0 = w1t + ((size_t)(n0 + wn + l15))*384 + lh*8;
  s16x8 bA[4], bB[4];
#pragma unroll
  for (int nf = 0; nf < 4; ++nf)
    bA[nf] = *reinterpret_cast<const s16x8*>(bp0 + (size_t)nf*16*384);
  for (int kc = 0; kc < 3; ++kc) {
#pragma unroll
    for (int p = 0; p < 8; ++p) {
      int off16 = p*256 + tid;
      int row = off16 >> 4, slot = off16 & 15;
      int sslot = slot ^ (row & 7);
      gl_lds16(h + ((size_t)(m0+row))*DIMD + kc*128 + sslot*8,
               (char*)als + off16*16);
    }
    __syncthreads();
#pragma unroll
    for (int kk = 0; kk < 4; ++kk) {
      int nko = (kk < 3) ? (kc*128 + (kk+1)*32) : ((kc < 2) ? (kc+1)*128 : -1);
      if (nko >= 0) {
        if (kk & 1) {
#pragma unroll
          for (int nf = 0; nf < 4; ++nf)
            bA[nf] = *reinterpret_cast<const s16x8*>(bp0 + (size_t)nf*16*384 + nko);
        } else {
#pragma unroll
          for (int nf = 0; nf < 4; ++nf)
            bB[nf] = *reinterpret_cast<const s16x8*>(bp0 + (size_t)nf*16*384 + nko);
        }
      }
#pragma unroll
      for (int mf = 0; mf < 4; ++mf) {
        s16x8 af = *reinterpret_cast<const s16x8*>(
            &als[(wm + mf*16 + l15)*128 + (((kk*4 + lh) ^ (l15 & 7))*8)]);
#pragma unroll
        for (int nf = 0; nf < 4; ++nf)
          acc[mf][nf] = __builtin_amdgcn_mfma_f32_16x16x32_bf16(
              af, (kk & 1) ? bB[nf] : bA[nf], acc[mf][nf], 0,0,0);
      }
    }
    __syncthreads();
  }
  float bias[4];
#pragma unroll
  for (int nf = 0; nf < 4; ++nf) bias[nf] = b1[n0 + wn + nf*16 + l15];
#pragma unroll
  for (int mf = 0; mf < 4; ++mf)
#pragma unroll
    for (int nf = 0; nf < 4; ++nf)
#pragma unroll
      for (int r = 0; r < 4; ++r) {
        int m = wm + mf*16 + lh*4 + r, ch = n0 + wn + nf*16 + l15;
        float v = acc[mf][nf][r] + bias[nf];
        v = v * sigf(v);
        ai[(size_t)(m0+m)*768 + ch] = __float2bfloat16(v);
      }
}

// ---------------- fused MLP GEMM2 + bias + residual + LN2 -> out f32 ----------------
// 512 threads (8 waves), M=64/block, grid 512. Wave w owns cols [w*48, w*48+48).
__global__ __launch_bounds__(512) void k_mlp2ln(const bf16* __restrict__ ai, const bf16* __restrict__ w2t,
                                                const float* __restrict__ b2, const float* __restrict__ x,
                                                const float* __restrict__ l2g, const float* __restrict__ l2b,
                                                float* __restrict__ out) {
  int raw = blockIdx.x;                 // 512
  int mt = (raw & 7)*64 + (raw >> 3);   // XCD swizzle
  int m0 = mt*64;
  __shared__ __align__(16) u16 als[8192];     // [64][128] bf16 A-stage (16KB)
  __shared__ float pls[8][64][2];             // per-wave row partials (4KB)
  int tid = threadIdx.x, w = tid >> 6, l = tid & 63, l15 = l & 15, lh = l >> 4;
  int wn = w*48;
  f32x4 zz = {0.f,0.f,0.f,0.f};
  f32x4 acc[4][3];
#pragma unroll
  for (int i=0;i<4;++i)
#pragma unroll
    for (int jn=0;jn<3;++jn) acc[i][jn]=zz;
  const bf16* bp0 = w2t + ((size_t)(wn + l15))*768 + lh*8;
  s16x8 bA[3], bB[3];
#pragma unroll
  for (int nf = 0; nf < 3; ++nf)
    bA[nf] = *reinterpret_cast<const s16x8*>(bp0 + (size_t)nf*16*768);
  for (int kc = 0; kc < 6; ++kc) {
#pragma unroll
    for (int p = 0; p < 2; ++p) {
      int off16 = p*512 + tid;              // 1024 chunks of 16B
      int row = off16 >> 4, slot = off16 & 15;
      int sslot = slot ^ (row & 7);
      gl_lds16(ai + ((size_t)(m0+row))*768 + kc*128 + sslot*8,
               (char*)als + off16*16);
    }
    __syncthreads();
#pragma unroll
    for (int kk = 0; kk < 4; ++kk) {
      int nko = (kk < 3) ? (kc*128 + (kk+1)*32) : ((kc < 5) ? (kc+1)*128 : -1);
      if (nko >= 0) {
        if (kk & 1) {
#pragma unroll
          for (int nf = 0; nf < 3; ++nf)
            bA[nf] = *reinterpret_cast<const s16x8*>(bp0 + (size_t)nf*16*768 + nko);
        } else {
#pragma unroll
          for (int nf = 0; nf < 3; ++nf)
            bB[nf] = *reinterpret_cast<const s16x8*>(bp0 + (size_t)nf*16*768 + nko);
        }
      }
#pragma unroll
      for (int mf = 0; mf < 4; ++mf) {
        s16x8 af = *reinterpret_cast<const s16x8*>(
            &als[(mf*16 + l15)*128 + (((kk*4 + lh) ^ (l15 & 7))*8)]);
#pragma unroll
        for (int nf = 0; nf < 3; ++nf)
          acc[mf][nf] = __builtin_amdgcn_mfma_f32_16x16x32_bf16(
              af, (kk & 1) ? bB[nf] : bA[nf], acc[mf][nf], 0,0,0);
      }
    }
    __syncthreads();
  }
  // epilogue: v = acc + b2 + x (in place), row stats, LN, store
  float bias[3];
#pragma unroll
  for (int nf = 0; nf < 3; ++nf) bias[nf] = b2[wn + nf*16 + l15];
#pragma unroll
  for (int mf = 0; mf < 4; ++mf) {
#pragma unroll
    for (int r = 0; r < 4; ++r) {
      int m = mf*16 + lh*4 + r;
      const float* xr = x + (size_t)(m0+m)*DIMD + wn + l15;
      float sa = 0.f, sb = 0.f;
#pragma unroll
      for (int nf = 0; nf < 3; ++nf) {
        float v = acc[mf][nf][r] + bias[nf] + xr[nf*16];
        acc[mf][nf][r] = v;
        sa += v; sb += v*v;
      }
#pragma unroll
      for (int off = 1; off < 16; off <<= 1) {
        sa += __shfl_xor(sa, off, 16);
        sb += __shfl_xor(sb, off, 16);
      }
      if (l15 == 0) { pls[w][m][0] = sa; pls[w][m][1] = sb; }
    }
  }
  __syncthreads();
  float lg[3], lb[3];
#pragma unroll
  for (int nf = 0; nf < 3; ++nf) { lg[nf] = l2g[wn + nf*16 + l15]; lb[nf] = l2b[wn + nf*16 + l15]; }
#pragma unroll
  for (int mf = 0; mf < 4; ++mf) {
#pragma unroll
    for (int r = 0; r < 4; ++r) {
      int m = mf*16 + lh*4 + r;
      float S1 = 0.f, S2 = 0.f;
#pragma unroll
      for (int ww = 0; ww < 8; ++ww) { S1 += pls[ww][m][0]; S2 += pls[ww][m][1]; }
      float mean = S1 * (1.f/384.f);
      float var = S2 * (1.f/384.f) - mean*mean;
      float rs = rsqrtf(var + 1e-5f);
      float* orow = out + (size_t)(m0+m)*DIMD + wn + l15;
#pragma unroll
      for (int nf = 0; nf < 3; ++nf)
        orow[nf*16] = (acc[mf][nf][r] - mean)*rs*lg[nf] + lb[nf];
    }
  }
}

extern "C" void kernel_launch(void* const* d_in, const int* in_sizes, int n_in,
                              void* d_out, int out_size, void* d_ws, size_t ws_size,
                              hipStream_t stream) {
  const float* x   = (const float*)d_in[0];
  const float* cw  = (const float*)d_in[1];
  const float* cb  = (const float*)d_in[2];
  const float* qw  = (const float*)d_in[3];
  const float* qb  = (const float*)d_in[4];
  const float* kw  = (const float*)d_in[5];
  const float* kb  = (const float*)d_in[6];
  const float* vw  = (const float*)d_in[7];
  const float* vb  = (const float*)d_in[8];
  const float* gw  = (const float*)d_in[9];
  const float* gb  = (const float*)d_in[10];
  const float* dec = (const float*)d_in[11];
  const float* l1g = (const float*)d_in[12];
  const float* l1b = (const float*)d_in[13];
  const float* w1  = (const float*)d_in[14];
  const float* b1  = (const float*)d_in[15];
  const float* w2  = (const float*)d_in[16];
  const float* b2  = (const float*)d_in[17];
  const float* l2g = (const float*)d_in[18];
  const float* l2b = (const float*)d_in[19];

  char* ws = (char*)d_ws;
  float* lam = (float*)(ws + OFF_LAM);
  bf16* wqt  = (bf16*)(ws + OFF_WQ);
  bf16* cwt  = (bf16*)(ws + OFF_CW);
  bf16* w1t  = (bf16*)(ws + OFF_W1T);
  bf16* w2t  = (bf16*)(ws + OFF_W2T);
  bf16* xc   = (bf16*)(ws + OFF_XC);
  bf16* q    = (bf16*)(ws + OFF_Q);
  bf16* u    = (bf16*)(ws + OFF_U);
  bf16* hbuf = (bf16*)(ws + OFF_H);
  bf16* ai   = (bf16*)(ws + OFF_AI);
  float* out = (float*)d_out;

  hipLaunchKernelGGL(k_prep_w,  dim3(1024), dim3(256), 0, stream, qw,kw,vw,gw,cw,w1,w2, wqt,cwt,w1t,w2t);
  hipLaunchKernelGGL(k_prep_lam,dim3(1),    dim3(384), 0, stream, dec, lam);
  hipLaunchKernelGGL(k_conv,    dim3(1536), dim3(256), 0, stream, x, cb, cwt, xc);
  hipLaunchKernelGGL(k_qkvg,    dim3(3072), dim3(256), 0, stream, xc, wqt, qb,kb,vb,gb, q, u);
  hipLaunchKernelGGL(k_scan,    dim3(256),  dim3(384), 0, stream, u, q, lam, l1g, l1b, hbuf);
  hipLaunchKernelGGL(k_mlp1,    dim3(1536), dim3(256), 0, stream, hbuf, w1t, b1, ai);
  hipLaunchKernelGGL(k_mlp2ln,  dim3(512),  dim3(512), 0, stream, ai, w2t, b2, x, l2g, l2b, out);
}

// Round 14
// 241.473 us; speedup vs baseline: 1.3404x; 1.3404x over previous
//
#include <hip/hip_runtime.h>
#include <hip/hip_bf16.h>

#define DIMD 384
#define SEQL 4096
#define NBATCH 8
#define NTOK (NBATCH*SEQL)

typedef float f32x4 __attribute__((ext_vector_type(4)));
typedef short s16x8 __attribute__((ext_vector_type(8)));
typedef unsigned short u16;
typedef __hip_bfloat16 bf16;

__device__ __forceinline__ float sigf(float x){ return 1.f/(1.f+__expf(-x)); }

// async global->LDS, 16B per lane. LDS dest must be wave-uniform base + lane*16.
typedef __attribute__((address_space(3))) void lds_void;
typedef const __attribute__((address_space(1))) void glb_void;
__device__ __forceinline__ void gl_lds16(const void* g, void* l) {
  __builtin_amdgcn_global_load_lds((glb_void*)g, (lds_void*)l, 16, 0, 0);
}

// ---------------- workspace layout (bytes) ----------------
#define OFF_LAM   0ul
#define OFF_WQ    4096ul                       // bf16 [1536][384]
#define OFF_CW    (OFF_WQ + 1179648ul)         // bf16 [384][448]
#define OFF_W1T   (OFF_CW + 344064ul)          // bf16 [768][384]
#define OFF_W2T   (OFF_W1T + 589824ul)         // bf16 [384][768]
#define OFF_XC    4194304ul                    // bf16 [32768][384]
#define OFF_Q     (OFF_XC + 25165824ul)        // bf16 [32768][384]
#define OFF_U     (OFF_XC + 50331648ul)        // bf16 [32768][384]
#define OFF_AI    OFF_U                        // bf16 [32768][768] (reuse after u dead)
#define OFF_H     (OFF_U + 50331648ul)         // bf16 [32768][384]
// total = 130,023,424 bytes

// ---------------- prep: weight transposes to [n][k] bf16 ----------------
__global__ void k_prep_w(const float* __restrict__ qw, const float* __restrict__ kw,
                         const float* __restrict__ vw, const float* __restrict__ gw,
                         const float* __restrict__ cw, const float* __restrict__ w1,
                         const float* __restrict__ w2,
                         bf16* __restrict__ wqt, bf16* __restrict__ cwt,
                         bf16* __restrict__ w1t, bf16* __restrict__ w2t) {
  const int total = 589824 + 172032 + 294912 + 294912;
  for (int j = blockIdx.x*blockDim.x + threadIdx.x; j < total; j += gridDim.x*blockDim.x) {
    if (j < 589824) {
      int n = j / 384, k = j % 384;
      int mat = n / 384;
      int np = n % 384;                        // (384 not pow2 -> %, not &)
      const float* W = (mat==0)?qw:(mat==1)?kw:(mat==2)?vw:gw;
      wqt[(size_t)n*384 + k] = __float2bfloat16(W[(size_t)k*384 + np]);
    } else if (j < 589824 + 172032) {
      int jj = j - 589824;
      int o = jj / 448, k = jj % 448;
      int kap = k >> 6, i = k & 63;
      cwt[(size_t)o*448 + k] = __float2bfloat16(cw[((size_t)o*64 + i)*7 + kap]);
    } else if (j < 589824 + 172032 + 294912) {
      int jj = j - (589824 + 172032);
      int n = jj / 384, k = jj % 384;
      w1t[(size_t)n*384 + k] = __float2bfloat16(w1[(size_t)k*768 + n]);
    } else {
      int jj = j - (589824 + 172032 + 294912);
      int n = jj / 768, k = jj % 768;
      w2t[(size_t)n*768 + k] = __float2bfloat16(w2[(size_t)k*384 + n]);
    }
  }
}

__global__ void k_prep_lam(const float* __restrict__ decay, float* __restrict__ lam) {
  __shared__ float red[6];
  int t = threadIdx.x; // 384 threads
  float v = sigf(decay[t]);
  for (int off = 32; off; off >>= 1) v += __shfl_xor(v, off, 64);
  if ((t & 63) == 0) red[t >> 6] = v;
  __syncthreads();
  if (t == 0) {
    float s = 0.f;
    for (int i = 0; i < 6; ++i) s += red[i];
    lam[0] = s * (1.f/384.f);
  }
}

// ---------------- grouped conv (k=7, groups=6) + silu -> xc bf16 ----------------
__global__ __launch_bounds__(256) void k_conv(const float* __restrict__ x, const float* __restrict__ cb,
                                              const bf16* __restrict__ cwt, bf16* __restrict__ xc) {
  int id = blockIdx.x;             // 1536 = 8 b * 32 st * 6 g
  int g = id % 6, st = (id/6) & 31, b = id / 192;
  int s0 = st * 128;
  __shared__ u16 xls[134*72];
  __shared__ u16 wls[64*456];
  int tid = threadIdx.x;
  for (int r0 = 0; r0 < 144; r0 += 16) {
    int row = r0 + (tid >> 4);
    if (row < 134) {
      int col = (tid & 15) * 4;
      int s = s0 - 3 + row;
      float4 v = make_float4(0.f,0.f,0.f,0.f);
      if (s >= 0 && s < SEQL)
        v = *reinterpret_cast<const float4*>(x + ((size_t)(b*SEQL + s))*DIMD + g*64 + col);
      u16* dst = &xls[row*72 + col];
      bf16 t0 = __float2bfloat16(v.x); dst[0] = *reinterpret_cast<u16*>(&t0);
      bf16 t1 = __float2bfloat16(v.y); dst[1] = *reinterpret_cast<u16*>(&t1);
      bf16 t2 = __float2bfloat16(v.z); dst[2] = *reinterpret_cast<u16*>(&t2);
      bf16 t3 = __float2bfloat16(v.w); dst[3] = *reinterpret_cast<u16*>(&t3);
    }
  }
  for (int i0 = 0; i0 < 28672; i0 += 1024) {
    int i = i0 + tid*4;
    int o = i / 448, k = i % 448;
    *reinterpret_cast<uint2*>(&wls[o*456 + k]) =
      *reinterpret_cast<const uint2*>(cwt + ((size_t)(g*64 + o))*448 + k);
  }
  __syncthreads();
  int w = tid >> 6, l = tid & 63, l15 = l & 15, lh = l >> 4;
  f32x4 zz = {0.f,0.f,0.f,0.f};
  f32x4 acc[2][4];
  for (int i=0;i<2;++i) for (int jn=0;jn<4;++jn) acc[i][jn]=zz;
  for (int kap = 0; kap < 7; ++kap) {
#pragma unroll
    for (int ic = 0; ic < 2; ++ic) {
      s16x8 a0 = *reinterpret_cast<const s16x8*>(&xls[(w*32 +  0 + l15 + kap)*72 + ic*32 + lh*8]);
      s16x8 a1 = *reinterpret_cast<const s16x8*>(&xls[(w*32 + 16 + l15 + kap)*72 + ic*32 + lh*8]);
#pragma unroll
      for (int nf = 0; nf < 4; ++nf) {
        s16x8 bfr = *reinterpret_cast<const s16x8*>(&wls[(nf*16 + l15)*456 + kap*64 + ic*32 + lh*8]);
        acc[0][nf] = __builtin_amdgcn_mfma_f32_16x16x32_bf16(a0, bfr, acc[0][nf], 0,0,0);
        acc[1][nf] = __builtin_amdgcn_mfma_f32_16x16x32_bf16(a1, bfr, acc[1][nf], 0,0,0);
      }
    }
  }
#pragma unroll
  for (int nf = 0; nf < 4; ++nf) {
    int ch = g*64 + nf*16 + l15;
    float bias = cb[ch];
#pragma unroll
    for (int mf = 0; mf < 2; ++mf) {
#pragma unroll
      for (int r = 0; r < 4; ++r) {
        int m = w*32 + mf*16 + lh*4 + r;
        float v = acc[mf][nf][r] + bias;
        v = v * sigf(v);
        xc[((size_t)(b*SEQL + s0 + m))*DIMD + ch] = __float2bfloat16(v);
      }
    }
  }
}

// ---------------- fused QKVG GEMM (R12 body): q (bf16) and u = v*sig(g)*k (bf16) -------------
// B-stream explicitly double-buffered in registers: prefetch kk+1's frags before kk's MFMAs.
__global__ __launch_bounds__(256) void k_qkvg(const bf16* __restrict__ xc, const bf16* __restrict__ wt,
    const float* __restrict__ qb, const float* __restrict__ kb,
    const float* __restrict__ vb, const float* __restrict__ gb,
    bf16* __restrict__ qout, bf16* __restrict__ uout) {
  int raw = blockIdx.x;                       // 3072
  int vv = (raw & 7)*384 + (raw >> 3);        // XCD swizzle
  int mt = vv / 12, ct = vv % 12;
  int m0 = mt*128, c0 = ct*32;
  __shared__ __align__(16) u16 smem[16384];   // 32KB: A-stage [128][128] / ex bf16 [3][128][40]
  u16* als = smem;
  int tid = threadIdx.x, w = tid >> 6, l = tid & 63, l15 = l & 15, lh = l >> 4;
  f32x4 zz = {0.f,0.f,0.f,0.f};
  f32x4 acc[8][2];
#pragma unroll
  for (int i=0;i<8;++i){ acc[i][0]=zz; acc[i][1]=zz; }
  const bf16* b0p = wt + ((size_t)(w*384 + c0 + l15))*384 + lh*8;
  const bf16* b1p = b0p + (size_t)16*384;
  s16x8 c0A = *reinterpret_cast<const s16x8*>(b0p);
  s16x8 c1A = *reinterpret_cast<const s16x8*>(b1p);
  s16x8 c0B, c1B;
  for (int kc = 0; kc < 3; ++kc) {
#pragma unroll
    for (int p = 0; p < 8; ++p) {
      int off16 = p*256 + tid;
      int row = off16 >> 4, slot = off16 & 15;
      int sslot = slot ^ (row & 7);
      gl_lds16(xc + ((size_t)(m0+row))*DIMD + kc*128 + sslot*8,
               (char*)als + off16*16);
    }
    __syncthreads();
#pragma unroll
    for (int kk = 0; kk < 4; ++kk) {
      s16x8 cur0 = (kk & 1) ? c0B : c0A;
      s16x8 cur1 = (kk & 1) ? c1B : c1A;
      int nko = (kk < 3) ? (kc*128 + (kk+1)*32) : ((kc < 2) ? (kc+1)*128 : -1);
      if (nko >= 0) {
        if (kk & 1) { c0A = *reinterpret_cast<const s16x8*>(b0p + nko);
                      c1A = *reinterpret_cast<const s16x8*>(b1p + nko); }
        else        { c0B = *reinterpret_cast<const s16x8*>(b0p + nko);
                      c1B = *reinterpret_cast<const s16x8*>(b1p + nko); }
      }
#pragma unroll
      for (int mf = 0; mf < 8; ++mf) {
        s16x8 af = *reinterpret_cast<const s16x8*>(
            &als[(mf*16 + l15)*128 + (((kk*4 + lh) ^ (l15 & 7))*8)]);
        acc[mf][0] = __builtin_amdgcn_mfma_f32_16x16x32_bf16(af, cur0, acc[mf][0], 0,0,0);
        acc[mf][1] = __builtin_amdgcn_mfma_f32_16x16x32_bf16(af, cur1, acc[mf][1], 0,0,0);
      }
    }
    __syncthreads();
  }
  const float* bp = (w==0)?qb:(w==1)?kb:(w==2)?vb:gb;
  float bias0 = bp[c0 + l15], bias1 = bp[c0 + 16 + l15];
  if (w == 0) {
#pragma unroll
    for (int mf=0;mf<8;++mf)
#pragma unroll
      for (int nf=0;nf<2;++nf) {
        float bs = nf ? bias1 : bias0;
#pragma unroll
        for (int r=0;r<4;++r) {
          int m = mf*16 + lh*4 + r, c = nf*16 + l15;
          qout[((size_t)(m0+m))*DIMD + c0 + c] = __float2bfloat16(acc[mf][nf][r] + bs);
        }
      }
  } else {
    u16* exm = smem + (size_t)(w-1)*(128*40);
#pragma unroll
    for (int mf=0;mf<8;++mf)
#pragma unroll
      for (int nf=0;nf<2;++nf) {
        float bs = nf ? bias1 : bias0;
#pragma unroll
        for (int r=0;r<4;++r) {
          int m = mf*16 + lh*4 + r, c = nf*16 + l15;
          bf16 t = __float2bfloat16(acc[mf][nf][r] + bs);
          exm[m*40 + c] = *reinterpret_cast<u16*>(&t);
        }
      }
  }
  __syncthreads();
#pragma unroll
  for (int p = 0; p < 16; ++p) {
    int idx = p*256 + tid;
    int m = idx >> 5, c = idx & 31;
    u16 kr = smem[0*(128*40) + m*40 + c];
    u16 vr = smem[1*(128*40) + m*40 + c];
    u16 gr = smem[2*(128*40) + m*40 + c];
    float kvv = __bfloat162float(*reinterpret_cast<bf16*>(&kr));
    float vvv = __bfloat162float(*reinterpret_cast<bf16*>(&vr));
    float gvv = __bfloat162float(*reinterpret_cast<bf16*>(&gr));
    uout[((size_t)(m0+m))*DIMD + c0 + c] = __float2bfloat16(vvv * sigf(gvv) * kvv);
  }
}

// ---------------- decayed cumsum + q*diag + LN1 -> h bf16 (48KB LDS, 3 blocks/CU) -------------
__global__ __launch_bounds__(384) void k_scan(const bf16* __restrict__ u, const bf16* __restrict__ q,
    const float* __restrict__ lam_p, const float* __restrict__ l1g, const float* __restrict__ l1b,
    bf16* __restrict__ h) {
  int b = blockIdx.x >> 5, c = blockIdx.x & 31; // 8 x 32
  int d = threadIdx.x;                          // 384
  float lam = lam_p[0];
  __shared__ float ols[32*384];                 // 48 KB
  __shared__ float lgs[384], lbs[384];
  lgs[d] = l1g[d]; lbs[d] = l1b[d];
  int s0 = c*128;
  size_t base = ((size_t)b*SEQL)*DIMD + d;
  float carry = 0.f;
  int sstart = s0 - 64; if (sstart < 0) sstart = 0;
  for (int s = sstart; s < s0; s += 8) {
    float uv[8];
#pragma unroll
    for (int j = 0; j < 8; ++j) uv[j] = __bfloat162float(u[base + (size_t)(s+j)*DIMD]);
#pragma unroll
    for (int j = 0; j < 8; ++j) carry = carry*lam + uv[j];
  }
  int w = d >> 6, lane = d & 63;
  for (int p = 0; p < 4; ++p) {
    int sb = s0 + p*32;
    __syncthreads();
    for (int it0 = 0; it0 < 32; it0 += 8) {
      float uv[8], qv[8];
#pragma unroll
      for (int j = 0; j < 8; ++j) uv[j] = __bfloat162float(u[base + (size_t)(sb+it0+j)*DIMD]);
#pragma unroll
      for (int j = 0; j < 8; ++j) qv[j] = __bfloat162float(q[base + (size_t)(sb+it0+j)*DIMD]);
#pragma unroll
      for (int j = 0; j < 8; ++j) {
        carry = carry*lam + uv[j];
        ols[(it0+j)*384 + d] = carry * qv[j];
      }
    }
    __syncthreads();
    for (int t = w; t < 32; t += 6) {
      float vv[6]; float s1 = 0.f, s2 = 0.f;
#pragma unroll
      for (int j = 0; j < 6; ++j) {
        vv[j] = ols[t*384 + j*64 + lane];
        s1 += vv[j]; s2 += vv[j]*vv[j];
      }
      for (int off = 32; off; off >>= 1) { s1 += __shfl_xor(s1, off, 64); s2 += __shfl_xor(s2, off, 64); }
      float mean = s1 * (1.f/384.f);
      float var = s2 * (1.f/384.f) - mean*mean;
      float rs = rsqrtf(var + 1e-5f);
      size_t rowo = ((size_t)(b*SEQL + sb + t))*DIMD;
#pragma unroll
      for (int j = 0; j < 6; ++j) {
        int dd = j*64 + lane;
        h[rowo + dd] = __float2bfloat16((vv[j]-mean)*rs*lgs[dd] + lbs[dd]);
      }
    }
  }
}

// ---------------- MLP GEMM1 + silu -> ai bf16 (R14: 8 waves, wave owns 64x32, B reg-dbuf) -----
__global__ __launch_bounds__(512) void k_mlp1(const bf16* __restrict__ h, const bf16* __restrict__ w1t,
                                              const float* __restrict__ b1, bf16* __restrict__ ai) {
  int raw = blockIdx.x;                 // 1536
  int vv = (raw & 7)*192 + (raw >> 3);
  int mt = vv / 6, nt = vv % 6;
  int m0 = mt*128, n0 = nt*128;
  __shared__ __align__(16) u16 als[16384];
  int tid = threadIdx.x, w = tid >> 6, l = tid & 63, l15 = l & 15, lh = l >> 4;
  int wm = (w >> 2)*64, wn = (w & 3)*32;
  f32x4 zz = {0.f,0.f,0.f,0.f};
  f32x4 acc[4][2];
#pragma unroll
  for (int i=0;i<4;++i) for (int jn=0;jn<2;++jn) acc[i][jn]=zz;
  const bf16* bp0 = w1t + ((size_t)(n0 + wn + l15))*384 + lh*8;
  s16x8 bA[2], bB[2];
#pragma unroll
  for (int nf = 0; nf < 2; ++nf)
    bA[nf] = *reinterpret_cast<const s16x8*>(bp0 + (size_t)nf*16*384);
  for (int kc = 0; kc < 3; ++kc) {
#pragma unroll
    for (int p = 0; p < 4; ++p) {
      int off16 = p*512 + tid;
      int row = off16 >> 4, slot = off16 & 15;
      int sslot = slot ^ (row & 7);
      gl_lds16(h + ((size_t)(m0+row))*DIMD + kc*128 + sslot*8,
               (char*)als + off16*16);
    }
    __syncthreads();
#pragma unroll
    for (int kk = 0; kk < 4; ++kk) {
      int nko = (kk < 3) ? (kc*128 + (kk+1)*32) : ((kc < 2) ? (kc+1)*128 : -1);
      if (nko >= 0) {
        if (kk & 1) {
#pragma unroll
          for (int nf = 0; nf < 2; ++nf)
            bA[nf] = *reinterpret_cast<const s16x8*>(bp0 + (size_t)nf*16*384 + nko);
        } else {
#pragma unroll
          for (int nf = 0; nf < 2; ++nf)
            bB[nf] = *reinterpret_cast<const s16x8*>(bp0 + (size_t)nf*16*384 + nko);
        }
      }
#pragma unroll
      for (int mf = 0; mf < 4; ++mf) {
        s16x8 af = *reinterpret_cast<const s16x8*>(
            &als[(wm + mf*16 + l15)*128 + (((kk*4 + lh) ^ (l15 & 7))*8)]);
#pragma unroll
        for (int nf = 0; nf < 2; ++nf)
          acc[mf][nf] = __builtin_amdgcn_mfma_f32_16x16x32_bf16(
              af, (kk & 1) ? bB[nf] : bA[nf], acc[mf][nf], 0,0,0);
      }
    }
    __syncthreads();
  }
  float bias[2];
#pragma unroll
  for (int nf = 0; nf < 2; ++nf) bias[nf] = b1[n0 + wn + nf*16 + l15];
#pragma unroll
  for (int mf = 0; mf < 4; ++mf)
#pragma unroll
    for (int nf = 0; nf < 2; ++nf)
#pragma unroll
      for (int r = 0; r < 4; ++r) {
        int m = wm + mf*16 + lh*4 + r, ch = n0 + wn + nf*16 + l15;
        float v = acc[mf][nf][r] + bias[nf];
        v = v * sigf(v);
        ai[(size_t)(m0+m)*768 + ch] = __float2bfloat16(v);
      }
}

// ---------------- fused MLP GEMM2 + bias + residual + LN2 -> out f32 ----------------
// 512 threads (8 waves), M=64/block, grid 512. Wave w owns cols [w*48, w*48+48).
__global__ __launch_bounds__(512) void k_mlp2ln(const bf16* __restrict__ ai, const bf16* __restrict__ w2t,
                                                const float* __restrict__ b2, const float* __restrict__ x,
                                                const float* __restrict__ l2g, const float* __restrict__ l2b,
                                                float* __restrict__ out) {
  int raw = blockIdx.x;                 // 512
  int mt = (raw & 7)*64 + (raw >> 3);   // XCD swizzle
  int m0 = mt*64;
  __shared__ __align__(16) u16 als[8192];     // [64][128] bf16 A-stage (16KB)
  __shared__ float pls[8][64][2];             // per-wave row partials (4KB)
  int tid = threadIdx.x, w = tid >> 6, l = tid & 63, l15 = l & 15, lh = l >> 4;
  int wn = w*48;
  f32x4 zz = {0.f,0.f,0.f,0.f};
  f32x4 acc[4][3];
#pragma unroll
  for (int i=0;i<4;++i)
#pragma unroll
    for (int jn=0;jn<3;++jn) acc[i][jn]=zz;
  const bf16* bp0 = w2t + ((size_t)(wn + l15))*768 + lh*8;
  s16x8 bA[3], bB[3];
#pragma unroll
  for (int nf = 0; nf < 3; ++nf)
    bA[nf] = *reinterpret_cast<const s16x8*>(bp0 + (size_t)nf*16*768);
  for (int kc = 0; kc < 6; ++kc) {
#pragma unroll
    for (int p = 0; p < 2; ++p) {
      int off16 = p*512 + tid;              // 1024 chunks of 16B
      int row = off16 >> 4, slot = off16 & 15;
      int sslot = slot ^ (row & 7);
      gl_lds16(ai + ((size_t)(m0+row))*768 + kc*128 + sslot*8,
               (char*)als + off16*16);
    }
    __syncthreads();
#pragma unroll
    for (int kk = 0; kk < 4; ++kk) {
      int nko = (kk < 3) ? (kc*128 + (kk+1)*32) : ((kc < 5) ? (kc+1)*128 : -1);
      if (nko >= 0) {
        if (kk & 1) {
#pragma unroll
          for (int nf = 0; nf < 3; ++nf)
            bA[nf] = *reinterpret_cast<const s16x8*>(bp0 + (size_t)nf*16*768 + nko);
        } else {
#pragma unroll
          for (int nf = 0; nf < 3; ++nf)
            bB[nf] = *reinterpret_cast<const s16x8*>(bp0 + (size_t)nf*16*768 + nko);
        }
      }
#pragma unroll
      for (int mf = 0; mf < 4; ++mf) {
        s16x8 af = *reinterpret_cast<const s16x8*>(
            &als[(mf*16 + l15)*128 + (((kk*4 + lh) ^ (l15 & 7))*8)]);
#pragma unroll
        for (int nf = 0; nf < 3; ++nf)
          acc[mf][nf] = __builtin_amdgcn_mfma_f32_16x16x32_bf16(
              af, (kk & 1) ? bB[nf] : bA[nf], acc[mf][nf], 0,0,0);
      }
    }
    __syncthreads();
  }
  // epilogue: v = acc + b2 + x (in place), row stats, LN, store
  float bias[3];
#pragma unroll
  for (int nf = 0; nf < 3; ++nf) bias[nf] = b2[wn + nf*16 + l15];
#pragma unroll
  for (int mf = 0; mf < 4; ++mf) {
#pragma unroll
    for (int r = 0; r < 4; ++r) {
      int m = mf*16 + lh*4 + r;
      const float* xr = x + (size_t)(m0+m)*DIMD + wn + l15;
      float sa = 0.f, sb = 0.f;
#pragma unroll
      for (int nf = 0; nf < 3; ++nf) {
        float v = acc[mf][nf][r] + bias[nf] + xr[nf*16];
        acc[mf][nf][r] = v;
        sa += v; sb += v*v;
      }
#pragma unroll
      for (int off = 1; off < 16; off <<= 1) {
        sa += __shfl_xor(sa, off, 16);
        sb += __shfl_xor(sb, off, 16);
      }
      if (l15 == 0) { pls[w][m][0] = sa; pls[w][m][1] = sb; }
    }
  }
  __syncthreads();
  float lg[3], lb[3];
#pragma unroll
  for (int nf = 0; nf < 3; ++nf) { lg[nf] = l2g[wn + nf*16 + l15]; lb[nf] = l2b[wn + nf*16 + l15]; }
#pragma unroll
  for (int mf = 0; mf < 4; ++mf) {
#pragma unroll
    for (int r = 0; r < 4; ++r) {
      int m = mf*16 + lh*4 + r;
      float S1 = 0.f, S2 = 0.f;
#pragma unroll
      for (int ww = 0; ww < 8; ++ww) { S1 += pls[ww][m][0]; S2 += pls[ww][m][1]; }
      float mean = S1 * (1.f/384.f);
      float var = S2 * (1.f/384.f) - mean*mean;
      float rs = rsqrtf(var + 1e-5f);
      float* orow = out + (size_t)(m0+m)*DIMD + wn + l15;
#pragma unroll
      for (int nf = 0; nf < 3; ++nf)
        orow[nf*16] = (acc[mf][nf][r] - mean)*rs*lg[nf] + lb[nf];
    }
  }
}

extern "C" void kernel_launch(void* const* d_in, const int* in_sizes, int n_in,
                              void* d_out, int out_size, void* d_ws, size_t ws_size,
                              hipStream_t stream) {
  const float* x   = (const float*)d_in[0];
  const float* cw  = (const float*)d_in[1];
  const float* cb  = (const float*)d_in[2];
  const float* qw  = (const float*)d_in[3];
  const float* qb  = (const float*)d_in[4];
  const float* kw  = (const float*)d_in[5];
  const float* kb  = (const float*)d_in[6];
  const float* vw  = (const float*)d_in[7];
  const float* vb  = (const float*)d_in[8];
  const float* gw  = (const float*)d_in[9];
  const float* gb  = (const float*)d_in[10];
  const float* dec = (const float*)d_in[11];
  const float* l1g = (const float*)d_in[12];
  const float* l1b = (const float*)d_in[13];
  const float* w1  = (const float*)d_in[14];
  const float* b1  = (const float*)d_in[15];
  const float* w2  = (const float*)d_in[16];
  const float* b2  = (const float*)d_in[17];
  const float* l2g = (const float*)d_in[18];
  const float* l2b = (const float*)d_in[19];

  char* ws = (char*)d_ws;
  float* lam = (float*)(ws + OFF_LAM);
  bf16* wqt  = (bf16*)(ws + OFF_WQ);
  bf16* cwt  = (bf16*)(ws + OFF_CW);
  bf16* w1t  = (bf16*)(ws + OFF_W1T);
  bf16* w2t  = (bf16*)(ws + OFF_W2T);
  bf16* xc   = (bf16*)(ws + OFF_XC);
  bf16* q    = (bf16*)(ws + OFF_Q);
  bf16* u    = (bf16*)(ws + OFF_U);
  bf16* hbuf = (bf16*)(ws + OFF_H);
  bf16* ai   = (bf16*)(ws + OFF_AI);
  float* out = (float*)d_out;

  hipLaunchKernelGGL(k_prep_w,  dim3(1024), dim3(256), 0, stream, qw,kw,vw,gw,cw,w1,w2, wqt,cwt,w1t,w2t);
  hipLaunchKernelGGL(k_prep_lam,dim3(1),    dim3(384), 0, stream, dec, lam);
  hipLaunchKernelGGL(k_conv,    dim3(1536), dim3(256), 0, stream, x, cb, cwt, xc);
  hipLaunchKernelGGL(k_qkvg,    dim3(3072), dim3(256), 0, stream, xc, wqt, qb,kb,vb,gb, q, u);
  hipLaunchKernelGGL(k_scan,    dim3(256),  dim3(384), 0, stream, u, q, lam, l1g, l1b, hbuf);
  hipLaunchKernelGGL(k_mlp1,    dim3(1536), dim3(512), 0, stream, hbuf, w1t, b1, ai);
  hipLaunchKernelGGL(k_mlp2ln,  dim3(512),  dim3(512), 0, stream, ai, w2t, b2, x, l2g, l2b, out);
}

// Round 15
// 240.572 us; speedup vs baseline: 1.3455x; 1.0037x over previous
//
#include <hip/hip_runtime.h>
#include <hip/hip_bf16.h>

#define DIMD 384
#define SEQL 4096
#define NBATCH 8
#define NTOK (NBATCH*SEQL)

typedef float f32x4 __attribute__((ext_vector_type(4)));
typedef short s16x8 __attribute__((ext_vector_type(8)));
typedef unsigned short u16;
typedef __hip_bfloat16 bf16;

__device__ __forceinline__ float sigf(float x){ return 1.f/(1.f+__expf(-x)); }

// async global->LDS, 16B per lane. LDS dest must be wave-uniform base + lane*16.
typedef __attribute__((address_space(3))) void lds_void;
typedef const __attribute__((address_space(1))) void glb_void;
__device__ __forceinline__ void gl_lds16(const void* g, void* l) {
  __builtin_amdgcn_global_load_lds((glb_void*)g, (lds_void*)l, 16, 0, 0);
}

// ---------------- workspace layout (bytes) ----------------
#define OFF_LAM   0ul
#define OFF_WQ    4096ul                       // bf16 [1536][384]
#define OFF_CW    (OFF_WQ + 1179648ul)         // bf16 [384][448]
#define OFF_W1T   (OFF_CW + 344064ul)          // bf16 [768][384]
#define OFF_W2T   (OFF_W1T + 589824ul)         // bf16 [384][768]
#define OFF_XC    4194304ul                    // bf16 [32768][384]
#define OFF_Q     (OFF_XC + 25165824ul)        // bf16 [32768][384]
#define OFF_U     (OFF_XC + 50331648ul)        // bf16 [32768][384]
#define OFF_AI    OFF_U                        // bf16 [32768][768] (reuse after u dead)
#define OFF_H     (OFF_U + 50331648ul)         // bf16 [32768][384]
// total = 130,023,424 bytes

// ---------------- prep: weight transposes to [n][k] bf16 ----------------
__global__ void k_prep_w(const float* __restrict__ qw, const float* __restrict__ kw,
                         const float* __restrict__ vw, const float* __restrict__ gw,
                         const float* __restrict__ cw, const float* __restrict__ w1,
                         const float* __restrict__ w2,
                         bf16* __restrict__ wqt, bf16* __restrict__ cwt,
                         bf16* __restrict__ w1t, bf16* __restrict__ w2t) {
  const int total = 589824 + 172032 + 294912 + 294912;
  for (int j = blockIdx.x*blockDim.x + threadIdx.x; j < total; j += gridDim.x*blockDim.x) {
    if (j < 589824) {
      int n = j / 384, k = j % 384;
      int mat = n / 384;
      int np = n % 384;                        // (384 not pow2 -> %, not &)
      const float* W = (mat==0)?qw:(mat==1)?kw:(mat==2)?vw:gw;
      wqt[(size_t)n*384 + k] = __float2bfloat16(W[(size_t)k*384 + np]);
    } else if (j < 589824 + 172032) {
      int jj = j - 589824;
      int o = jj / 448, k = jj % 448;
      int kap = k >> 6, i = k & 63;
      cwt[(size_t)o*448 + k] = __float2bfloat16(cw[((size_t)o*64 + i)*7 + kap]);
    } else if (j < 589824 + 172032 + 294912) {
      int jj = j - (589824 + 172032);
      int n = jj / 384, k = jj % 384;
      w1t[(size_t)n*384 + k] = __float2bfloat16(w1[(size_t)k*768 + n]);
    } else {
      int jj = j - (589824 + 172032 + 294912);
      int n = jj / 768, k = jj % 768;
      w2t[(size_t)n*768 + k] = __float2bfloat16(w2[(size_t)k*384 + n]);
    }
  }
}

__global__ void k_prep_lam(const float* __restrict__ decay, float* __restrict__ lam) {
  __shared__ float red[6];
  int t = threadIdx.x; // 384 threads
  float v = sigf(decay[t]);
  for (int off = 32; off; off >>= 1) v += __shfl_xor(v, off, 64);
  if ((t & 63) == 0) red[t >> 6] = v;
  __syncthreads();
  if (t == 0) {
    float s = 0.f;
    for (int i = 0; i < 6; ++i) s += red[i];
    lam[0] = s * (1.f/384.f);
  }
}

// ---------------- grouped conv (k=7, groups=6) + silu -> xc bf16 ----------------
__global__ __launch_bounds__(256) void k_conv(const float* __restrict__ x, const float* __restrict__ cb,
                                              const bf16* __restrict__ cwt, bf16* __restrict__ xc) {
  int id = blockIdx.x;             // 1536 = 8 b * 32 st * 6 g
  int g = id % 6, st = (id/6) & 31, b = id / 192;
  int s0 = st * 128;
  __shared__ u16 xls[134*72];
  __shared__ u16 wls[64*456];
  int tid = threadIdx.x;
  for (int r0 = 0; r0 < 144; r0 += 16) {
    int row = r0 + (tid >> 4);
    if (row < 134) {
      int col = (tid & 15) * 4;
      int s = s0 - 3 + row;
      float4 v = make_float4(0.f,0.f,0.f,0.f);
      if (s >= 0 && s < SEQL)
        v = *reinterpret_cast<const float4*>(x + ((size_t)(b*SEQL + s))*DIMD + g*64 + col);
      u16* dst = &xls[row*72 + col];
      bf16 t0 = __float2bfloat16(v.x); dst[0] = *reinterpret_cast<u16*>(&t0);
      bf16 t1 = __float2bfloat16(v.y); dst[1] = *reinterpret_cast<u16*>(&t1);
      bf16 t2 = __float2bfloat16(v.z); dst[2] = *reinterpret_cast<u16*>(&t2);
      bf16 t3 = __float2bfloat16(v.w); dst[3] = *reinterpret_cast<u16*>(&t3);
    }
  }
  for (int i0 = 0; i0 < 28672; i0 += 1024) {
    int i = i0 + tid*4;
    int o = i / 448, k = i % 448;
    *reinterpret_cast<uint2*>(&wls[o*456 + k]) =
      *reinterpret_cast<const uint2*>(cwt + ((size_t)(g*64 + o))*448 + k);
  }
  __syncthreads();
  int w = tid >> 6, l = tid & 63, l15 = l & 15, lh = l >> 4;
  f32x4 zz = {0.f,0.f,0.f,0.f};
  f32x4 acc[2][4];
  for (int i=0;i<2;++i) for (int jn=0;jn<4;++jn) acc[i][jn]=zz;
  for (int kap = 0; kap < 7; ++kap) {
#pragma unroll
    for (int ic = 0; ic < 2; ++ic) {
      s16x8 a0 = *reinterpret_cast<const s16x8*>(&xls[(w*32 +  0 + l15 + kap)*72 + ic*32 + lh*8]);
      s16x8 a1 = *reinterpret_cast<const s16x8*>(&xls[(w*32 + 16 + l15 + kap)*72 + ic*32 + lh*8]);
#pragma unroll
      for (int nf = 0; nf < 4; ++nf) {
        s16x8 bfr = *reinterpret_cast<const s16x8*>(&wls[(nf*16 + l15)*456 + kap*64 + ic*32 + lh*8]);
        acc[0][nf] = __builtin_amdgcn_mfma_f32_16x16x32_bf16(a0, bfr, acc[0][nf], 0,0,0);
        acc[1][nf] = __builtin_amdgcn_mfma_f32_16x16x32_bf16(a1, bfr, acc[1][nf], 0,0,0);
      }
    }
  }
#pragma unroll
  for (int nf = 0; nf < 4; ++nf) {
    int ch = g*64 + nf*16 + l15;
    float bias = cb[ch];
#pragma unroll
    for (int mf = 0; mf < 2; ++mf) {
#pragma unroll
      for (int r = 0; r < 4; ++r) {
        int m = w*32 + mf*16 + lh*4 + r;
        float v = acc[mf][nf][r] + bias;
        v = v * sigf(v);
        xc[((size_t)(b*SEQL + s0 + m))*DIMD + ch] = __float2bfloat16(v);
      }
    }
  }
}

// ---------------- fused QKVG GEMM (R15): T3 stage-ahead dbuf, BK=64, 1 barrier/tile ----------
// LDS 32KB = 2 x [128][64] bf16 (8-slot XOR swizzle); exchange [3][128][40] overlays after loop.
__global__ __launch_bounds__(256) void k_qkvg(const bf16* __restrict__ xc, const bf16* __restrict__ wt,
    const float* __restrict__ qb, const float* __restrict__ kb,
    const float* __restrict__ vb, const float* __restrict__ gb,
    bf16* __restrict__ qout, bf16* __restrict__ uout) {
  int raw = blockIdx.x;                       // 3072
  int vv = (raw & 7)*384 + (raw >> 3);        // XCD swizzle
  int mt = vv / 12, ct = vv % 12;
  int m0 = mt*128, c0 = ct*32;
  __shared__ __align__(16) u16 smem[16384];   // 32KB dbuf / exchange overlay
  int tid = threadIdx.x, w = tid >> 6, l = tid & 63, l15 = l & 15, lh = l >> 4;
  f32x4 zz = {0.f,0.f,0.f,0.f};
  f32x4 acc[8][2];
#pragma unroll
  for (int i=0;i<8;++i){ acc[i][0]=zz; acc[i][1]=zz; }
  const bf16* b0p = wt + ((size_t)(w*384 + c0 + l15))*384 + lh*8;
  const bf16* b1p = b0p + (size_t)16*384;
  s16x8 c0A = *reinterpret_cast<const s16x8*>(b0p);
  s16x8 c1A = *reinterpret_cast<const s16x8*>(b1p);
  s16x8 c0B, c1B;
  // prologue: tile 0 -> buf0
#pragma unroll
  for (int p = 0; p < 4; ++p) {
    int off16 = p*256 + tid;
    int row = off16 >> 3, slot = off16 & 7;
    int ss = slot ^ (row & 7);
    gl_lds16(xc + ((size_t)(m0+row))*DIMD + ss*8, (char*)smem + off16*16);
  }
  __syncthreads();
  for (int kc = 0; kc < 6; ++kc) {
    const u16* cur = smem + (kc & 1)*8192;
    // issue next-tile stage BEFORE compute; its drain happens at the barrier AFTER compute
    if (kc < 5) {
      char* nxt = (char*)(smem + ((kc & 1)^1)*8192);
#pragma unroll
      for (int p = 0; p < 4; ++p) {
        int off16 = p*256 + tid;
        int row = off16 >> 3, slot = off16 & 7;
        int ss = slot ^ (row & 7);
        gl_lds16(xc + ((size_t)(m0+row))*DIMD + (kc+1)*64 + ss*8, nxt + off16*16);
      }
    }
#pragma unroll
    for (int kk = 0; kk < 2; ++kk) {
      s16x8 cur0 = kk ? c0B : c0A;
      s16x8 cur1 = kk ? c1B : c1A;
      int nko = (kk == 0) ? (kc*64 + 32) : ((kc < 5) ? (kc+1)*64 : -1);
      if (nko >= 0) {
        if (kk) { c0A = *reinterpret_cast<const s16x8*>(b0p + nko);
                  c1A = *reinterpret_cast<const s16x8*>(b1p + nko); }
        else    { c0B = *reinterpret_cast<const s16x8*>(b0p + nko);
                  c1B = *reinterpret_cast<const s16x8*>(b1p + nko); }
      }
#pragma unroll
      for (int mf = 0; mf < 8; ++mf) {
        s16x8 af = *reinterpret_cast<const s16x8*>(
            &cur[(mf*16 + l15)*64 + (((kk*4 + lh) ^ (l15 & 7))*8)]);
        acc[mf][0] = __builtin_amdgcn_mfma_f32_16x16x32_bf16(af, cur0, acc[mf][0], 0,0,0);
        acc[mf][1] = __builtin_amdgcn_mfma_f32_16x16x32_bf16(af, cur1, acc[mf][1], 0,0,0);
      }
    }
    __syncthreads();   // drains vmcnt (next tile staged) + all waves done reading cur
  }
  const float* bp = (w==0)?qb:(w==1)?kb:(w==2)?vb:gb;
  float bias0 = bp[c0 + l15], bias1 = bp[c0 + 16 + l15];
  if (w == 0) {
#pragma unroll
    for (int mf=0;mf<8;++mf)
#pragma unroll
      for (int nf=0;nf<2;++nf) {
        float bs = nf ? bias1 : bias0;
#pragma unroll
        for (int r=0;r<4;++r) {
          int m = mf*16 + lh*4 + r, c = nf*16 + l15;
          qout[((size_t)(m0+m))*DIMD + c0 + c] = __float2bfloat16(acc[mf][nf][r] + bs);
        }
      }
  } else {
    u16* exm = smem + (size_t)(w-1)*(128*40);
#pragma unroll
    for (int mf=0;mf<8;++mf)
#pragma unroll
      for (int nf=0;nf<2;++nf) {
        float bs = nf ? bias1 : bias0;
#pragma unroll
        for (int r=0;r<4;++r) {
          int m = mf*16 + lh*4 + r, c = nf*16 + l15;
          bf16 t = __float2bfloat16(acc[mf][nf][r] + bs);
          exm[m*40 + c] = *reinterpret_cast<u16*>(&t);
        }
      }
  }
  __syncthreads();
#pragma unroll
  for (int p = 0; p < 16; ++p) {
    int idx = p*256 + tid;
    int m = idx >> 5, c = idx & 31;
    u16 kr = smem[0*(128*40) + m*40 + c];
    u16 vr = smem[1*(128*40) + m*40 + c];
    u16 gr = smem[2*(128*40) + m*40 + c];
    float kvv = __bfloat162float(*reinterpret_cast<bf16*>(&kr));
    float vvv = __bfloat162float(*reinterpret_cast<bf16*>(&vr));
    float gvv = __bfloat162float(*reinterpret_cast<bf16*>(&gr));
    uout[((size_t)(m0+m))*DIMD + c0 + c] = __float2bfloat16(vvv * sigf(gvv) * kvv);
  }
}

// ---------------- decayed cumsum + q*diag + LN1 -> h bf16 (48KB LDS, 3 blocks/CU) -------------
__global__ __launch_bounds__(384) void k_scan(const bf16* __restrict__ u, const bf16* __restrict__ q,
    const float* __restrict__ lam_p, const float* __restrict__ l1g, const float* __restrict__ l1b,
    bf16* __restrict__ h) {
  int b = blockIdx.x >> 5, c = blockIdx.x & 31; // 8 x 32
  int d = threadIdx.x;                          // 384
  float lam = lam_p[0];
  __shared__ float ols[32*384];                 // 48 KB
  __shared__ float lgs[384], lbs[384];
  lgs[d] = l1g[d]; lbs[d] = l1b[d];
  int s0 = c*128;
  size_t base = ((size_t)b*SEQL)*DIMD + d;
  float carry = 0.f;
  int sstart = s0 - 64; if (sstart < 0) sstart = 0;
  for (int s = sstart; s < s0; s += 8) {
    float uv[8];
#pragma unroll
    for (int j = 0; j < 8; ++j) uv[j] = __bfloat162float(u[base + (size_t)(s+j)*DIMD]);
#pragma unroll
    for (int j = 0; j < 8; ++j) carry = carry*lam + uv[j];
  }
  int w = d >> 6, lane = d & 63;
  for (int p = 0; p < 4; ++p) {
    int sb = s0 + p*32;
    __syncthreads();
    for (int it0 = 0; it0 < 32; it0 += 8) {
      float uv[8], qv[8];
#pragma unroll
      for (int j = 0; j < 8; ++j) uv[j] = __bfloat162float(u[base + (size_t)(sb+it0+j)*DIMD]);
#pragma unroll
      for (int j = 0; j < 8; ++j) qv[j] = __bfloat162float(q[base + (size_t)(sb+it0+j)*DIMD]);
#pragma unroll
      for (int j = 0; j < 8; ++j) {
        carry = carry*lam + uv[j];
        ols[(it0+j)*384 + d] = carry * qv[j];
      }
    }
    __syncthreads();
    for (int t = w; t < 32; t += 6) {
      float vv[6]; float s1 = 0.f, s2 = 0.f;
#pragma unroll
      for (int j = 0; j < 6; ++j) {
        vv[j] = ols[t*384 + j*64 + lane];
        s1 += vv[j]; s2 += vv[j]*vv[j];
      }
      for (int off = 32; off; off >>= 1) { s1 += __shfl_xor(s1, off, 64); s2 += __shfl_xor(s2, off, 64); }
      float mean = s1 * (1.f/384.f);
      float var = s2 * (1.f/384.f) - mean*mean;
      float rs = rsqrtf(var + 1e-5f);
      size_t rowo = ((size_t)(b*SEQL + sb + t))*DIMD;
#pragma unroll
      for (int j = 0; j < 6; ++j) {
        int dd = j*64 + lane;
        h[rowo + dd] = __float2bfloat16((vv[j]-mean)*rs*lgs[dd] + lbs[dd]);
      }
    }
  }
}

// ---------------- MLP GEMM1 + silu -> ai bf16 (R15: T3 stage-ahead dbuf, BK=64) --------------
__global__ __launch_bounds__(512) void k_mlp1(const bf16* __restrict__ h, const bf16* __restrict__ w1t,
                                              const float* __restrict__ b1, bf16* __restrict__ ai) {
  int raw = blockIdx.x;                 // 1536
  int vv = (raw & 7)*192 + (raw >> 3);
  int mt = vv / 6, nt = vv % 6;
  int m0 = mt*128, n0 = nt*128;
  __shared__ __align__(16) u16 als[16384];   // 32KB = 2 x [128][64]
  int tid = threadIdx.x, w = tid >> 6, l = tid & 63, l15 = l & 15, lh = l >> 4;
  int wm = (w >> 2)*64, wn = (w & 3)*32;
  f32x4 zz = {0.f,0.f,0.f,0.f};
  f32x4 acc[4][2];
#pragma unroll
  for (int i=0;i<4;++i) for (int jn=0;jn<2;++jn) acc[i][jn]=zz;
  const bf16* bp0 = w1t + ((size_t)(n0 + wn + l15))*384 + lh*8;
  s16x8 bA[2], bB[2];
#pragma unroll
  for (int nf = 0; nf < 2; ++nf)
    bA[nf] = *reinterpret_cast<const s16x8*>(bp0 + (size_t)nf*16*384);
  // prologue: tile 0 -> buf0
#pragma unroll
  for (int p = 0; p < 2; ++p) {
    int off16 = p*512 + tid;
    int row = off16 >> 3, slot = off16 & 7;
    int ss = slot ^ (row & 7);
    gl_lds16(h + ((size_t)(m0+row))*DIMD + ss*8, (char*)als + off16*16);
  }
  __syncthreads();
  for (int kc = 0; kc < 6; ++kc) {
    const u16* cur = als + (kc & 1)*8192;
    if (kc < 5) {
      char* nxt = (char*)(als + ((kc & 1)^1)*8192);
#pragma unroll
      for (int p = 0; p < 2; ++p) {
        int off16 = p*512 + tid;
        int row = off16 >> 3, slot = off16 & 7;
        int ss = slot ^ (row & 7);
        gl_lds16(h + ((size_t)(m0+row))*DIMD + (kc+1)*64 + ss*8, nxt + off16*16);
      }
    }
#pragma unroll
    for (int kk = 0; kk < 2; ++kk) {
      int nko = (kk == 0) ? (kc*64 + 32) : ((kc < 5) ? (kc+1)*64 : -1);
      if (nko >= 0) {
        if (kk) {
#pragma unroll
          for (int nf = 0; nf < 2; ++nf)
            bA[nf] = *reinterpret_cast<const s16x8*>(bp0 + (size_t)nf*16*384 + nko);
        } else {
#pragma unroll
          for (int nf = 0; nf < 2; ++nf)
            bB[nf] = *reinterpret_cast<const s16x8*>(bp0 + (size_t)nf*16*384 + nko);
        }
      }
#pragma unroll
      for (int mf = 0; mf < 4; ++mf) {
        s16x8 af = *reinterpret_cast<const s16x8*>(
            &cur[(wm + mf*16 + l15)*64 + (((kk*4 + lh) ^ (l15 & 7))*8)]);
#pragma unroll
        for (int nf = 0; nf < 2; ++nf)
          acc[mf][nf] = __builtin_amdgcn_mfma_f32_16x16x32_bf16(
              af, kk ? bB[nf] : bA[nf], acc[mf][nf], 0,0,0);
      }
    }
    __syncthreads();
  }
  float bias[2];
#pragma unroll
  for (int nf = 0; nf < 2; ++nf) bias[nf] = b1[n0 + wn + nf*16 + l15];
#pragma unroll
  for (int mf = 0; mf < 4; ++mf)
#pragma unroll
    for (int nf = 0; nf < 2; ++nf)
#pragma unroll
      for (int r = 0; r < 4; ++r) {
        int m = wm + mf*16 + lh*4 + r, ch = n0 + wn + nf*16 + l15;
        float v = acc[mf][nf][r] + bias[nf];
        v = v * sigf(v);
        ai[(size_t)(m0+m)*768 + ch] = __float2bfloat16(v);
      }
}

// ---------------- fused MLP GEMM2 + bias + residual + LN2 -> out f32 (R15: T3 dbuf) ----------
// 512 threads (8 waves), M=64/block, grid 512. Wave w owns cols [w*48, w*48+48).
__global__ __launch_bounds__(512) void k_mlp2ln(const bf16* __restrict__ ai, const bf16* __restrict__ w2t,
                                                const float* __restrict__ b2, const float* __restrict__ x,
                                                const float* __restrict__ l2g, const float* __restrict__ l2b,
                                                float* __restrict__ out) {
  int raw = blockIdx.x;                 // 512
  int mt = (raw & 7)*64 + (raw >> 3);   // XCD swizzle
  int m0 = mt*64;
  __shared__ __align__(16) u16 als[16384];    // 32KB = 2 x [64][128]
  __shared__ float pls[8][64][2];             // per-wave row partials (4KB)
  int tid = threadIdx.x, w = tid >> 6, l = tid & 63, l15 = l & 15, lh = l >> 4;
  int wn = w*48;
  f32x4 zz = {0.f,0.f,0.f,0.f};
  f32x4 acc[4][3];
#pragma unroll
  for (int i=0;i<4;++i)
#pragma unroll
    for (int jn=0;jn<3;++jn) acc[i][jn]=zz;
  const bf16* bp0 = w2t + ((size_t)(wn + l15))*768 + lh*8;
  s16x8 bA[3], bB[3];
#pragma unroll
  for (int nf = 0; nf < 3; ++nf)
    bA[nf] = *reinterpret_cast<const s16x8*>(bp0 + (size_t)nf*16*768);
  // prologue: tile 0 -> buf0
#pragma unroll
  for (int p = 0; p < 2; ++p) {
    int off16 = p*512 + tid;
    int row = off16 >> 4, slot = off16 & 15;
    int ss = slot ^ (row & 7);
    gl_lds16(ai + ((size_t)(m0+row))*768 + ss*8, (char*)als + off16*16);
  }
  __syncthreads();
  for (int kc = 0; kc < 6; ++kc) {
    const u16* cur = als + (kc & 1)*8192;
    if (kc < 5) {
      char* nxt = (char*)(als + ((kc & 1)^1)*8192);
#pragma unroll
      for (int p = 0; p < 2; ++p) {
        int off16 = p*512 + tid;
        int row = off16 >> 4, slot = off16 & 15;
        int ss = slot ^ (row & 7);
        gl_lds16(ai + ((size_t)(m0+row))*768 + (kc+1)*128 + ss*8, nxt + off16*16);
      }
    }
#pragma unroll
    for (int kk = 0; kk < 4; ++kk) {
      int nko = (kk < 3) ? (kc*128 + (kk+1)*32) : ((kc < 5) ? (kc+1)*128 : -1);
      if (nko >= 0) {
        if (kk & 1) {
#pragma unroll
          for (int nf = 0; nf < 3; ++nf)
            bA[nf] = *reinterpret_cast<const s16x8*>(bp0 + (size_t)nf*16*768 + nko);
        } else {
#pragma unroll
          for (int nf = 0; nf < 3; ++nf)
            bB[nf] = *reinterpret_cast<const s16x8*>(bp0 + (size_t)nf*16*768 + nko);
        }
      }
#pragma unroll
      for (int mf = 0; mf < 4; ++mf) {
        s16x8 af = *reinterpret_cast<const s16x8*>(
            &cur[(mf*16 + l15)*128 + (((kk*4 + lh) ^ (l15 & 7))*8)]);
#pragma unroll
        for (int nf = 0; nf < 3; ++nf)
          acc[mf][nf] = __builtin_amdgcn_mfma_f32_16x16x32_bf16(
              af, (kk & 1) ? bB[nf] : bA[nf], acc[mf][nf], 0,0,0);
      }
    }
    __syncthreads();
  }
  // epilogue: v = acc + b2 + x (in place), row stats, LN, store
  float bias[3];
#pragma unroll
  for (int nf = 0; nf < 3; ++nf) bias[nf] = b2[wn + nf*16 + l15];
#pragma unroll
  for (int mf = 0; mf < 4; ++mf) {
#pragma unroll
    for (int r = 0; r < 4; ++r) {
      int m = mf*16 + lh*4 + r;
      const float* xr = x + (size_t)(m0+m)*DIMD + wn + l15;
      float sa = 0.f, sb = 0.f;
#pragma unroll
      for (int nf = 0; nf < 3; ++nf) {
        float v = acc[mf][nf][r] + bias[nf] + xr[nf*16];
        acc[mf][nf][r] = v;
        sa += v; sb += v*v;
      }
#pragma unroll
      for (int off = 1; off < 16; off <<= 1) {
        sa += __shfl_xor(sa, off, 16);
        sb += __shfl_xor(sb, off, 16);
      }
      if (l15 == 0) { pls[w][m][0] = sa; pls[w][m][1] = sb; }
    }
  }
  __syncthreads();
  float lg[3], lb[3];
#pragma unroll
  for (int nf = 0; nf < 3; ++nf) { lg[nf] = l2g[wn + nf*16 + l15]; lb[nf] = l2b[wn + nf*16 + l15]; }
#pragma unroll
  for (int mf = 0; mf < 4; ++mf) {
#pragma unroll
    for (int r = 0; r < 4; ++r) {
      int m = mf*16 + lh*4 + r;
      float S1 = 0.f, S2 = 0.f;
#pragma unroll
      for (int ww = 0; ww < 8; ++ww) { S1 += pls[ww][m][0]; S2 += pls[ww][m][1]; }
      float mean = S1 * (1.f/384.f);
      float var = S2 * (1.f/384.f) - mean*mean;
      float rs = rsqrtf(var + 1e-5f);
      float* orow = out + (size_t)(m0+m)*DIMD + wn + l15;
#pragma unroll
      for (int nf = 0; nf < 3; ++nf)
        orow[nf*16] = (acc[mf][nf][r] - mean)*rs*lg[nf] + lb[nf];
    }
  }
}

extern "C" void kernel_launch(void* const* d_in, const int* in_sizes, int n_in,
                              void* d_out, int out_size, void* d_ws, size_t ws_size,
                              hipStream_t stream) {
  const float* x   = (const float*)d_in[0];
  const float* cw  = (const float*)d_in[1];
  const float* cb  = (const float*)d_in[2];
  const float* qw  = (const float*)d_in[3];
  const float* qb  = (const float*)d_in[4];
  const float* kw  = (const float*)d_in[5];
  const float* kb  = (const float*)d_in[6];
  const float* vw  = (const float*)d_in[7];
  const float* vb  = (const float*)d_in[8];
  const float* gw  = (const float*)d_in[9];
  const float* gb  = (const float*)d_in[10];
  const float* dec = (const float*)d_in[11];
  const float* l1g = (const float*)d_in[12];
  const float* l1b = (const float*)d_in[13];
  const float* w1  = (const float*)d_in[14];
  const float* b1  = (const float*)d_in[15];
  const float* w2  = (const float*)d_in[16];
  const float* b2  = (const float*)d_in[17];
  const float* l2g = (const float*)d_in[18];
  const float* l2b = (const float*)d_in[19];

  char* ws = (char*)d_ws;
  float* lam = (float*)(ws + OFF_LAM);
  bf16* wqt  = (bf16*)(ws + OFF_WQ);
  bf16* cwt  = (bf16*)(ws + OFF_CW);
  bf16* w1t  = (bf16*)(ws + OFF_W1T);
  bf16* w2t  = (bf16*)(ws + OFF_W2T);
  bf16* xc   = (bf16*)(ws + OFF_XC);
  bf16* q    = (bf16*)(ws + OFF_Q);
  bf16* u    = (bf16*)(ws + OFF_U);
  bf16* hbuf = (bf16*)(ws + OFF_H);
  bf16* ai   = (bf16*)(ws + OFF_AI);
  float* out = (float*)d_out;

  hipLaunchKernelGGL(k_prep_w,  dim3(1024), dim3(256), 0, stream, qw,kw,vw,gw,cw,w1,w2, wqt,cwt,w1t,w2t);
  hipLaunchKernelGGL(k_prep_lam,dim3(1),    dim3(384), 0, stream, dec, lam);
  hipLaunchKernelGGL(k_conv,    dim3(1536), dim3(256), 0, stream, x, cb, cwt, xc);
  hipLaunchKernelGGL(k_qkvg,    dim3(3072), dim3(256), 0, stream, xc, wqt, qb,kb,vb,gb, q, u);
  hipLaunchKernelGGL(k_scan,    dim3(256),  dim3(384), 0, stream, u, q, lam, l1g, l1b, hbuf);
  hipLaunchKernelGGL(k_mlp1,    dim3(1536), dim3(512), 0, stream, hbuf, w1t, b1, ai);
  hipLaunchKernelGGL(k_mlp2ln,  dim3(512),  dim3(512), 0, stream, ai, w2t, b2, x, l2g, l2b, out);
}

// Round 16
// 239.327 us; speedup vs baseline: 1.3525x; 1.0052x over previous
//
#include <hip/hip_runtime.h>
#include <hip/hip_bf16.h>

#define DIMD 384
#define SEQL 4096
#define NBATCH 8
#define NTOK (NBATCH*SEQL)

typedef float f32x4 __attribute__((ext_vector_type(4)));
typedef short s16x8 __attribute__((ext_vector_type(8)));
typedef unsigned short u16;
typedef __hip_bfloat16 bf16;

__device__ __forceinline__ float sigf(float x){ return 1.f/(1.f+__expf(-x)); }

// async global->LDS, 16B per lane. LDS dest must be wave-uniform base + lane*16.
typedef __attribute__((address_space(3))) void lds_void;
typedef const __attribute__((address_space(1))) void glb_void;
__device__ __forceinline__ void gl_lds16(const void* g, void* l) {
  __builtin_amdgcn_global_load_lds((glb_void*)g, (lds_void*)l, 16, 0, 0);
}

// ---------------- workspace layout (bytes) ----------------
#define OFF_LAM   0ul
#define OFF_WQ    4096ul                       // bf16 [1536][384]
#define OFF_CW    (OFF_WQ + 1179648ul)         // bf16 [384][448]
#define OFF_W1T   (OFF_CW + 344064ul)          // bf16 [768][384]
#define OFF_W2T   (OFF_W1T + 589824ul)         // bf16 [384][768]
#define OFF_XC    4194304ul                    // bf16 [32768][384]
#define OFF_Q     (OFF_XC + 25165824ul)        // bf16 [32768][384]
#define OFF_U     (OFF_XC + 50331648ul)        // bf16 [32768][384]
#define OFF_AI    OFF_U                        // bf16 [32768][768] (reuse after u dead)
#define OFF_H     (OFF_U + 50331648ul)         // bf16 [32768][384]
// total = 130,023,424 bytes

// ---------------- prep: weight transposes to [n][k] bf16 ----------------
__global__ void k_prep_w(const float* __restrict__ qw, const float* __restrict__ kw,
                         const float* __restrict__ vw, const float* __restrict__ gw,
                         const float* __restrict__ cw, const float* __restrict__ w1,
                         const float* __restrict__ w2,
                         bf16* __restrict__ wqt, bf16* __restrict__ cwt,
                         bf16* __restrict__ w1t, bf16* __restrict__ w2t) {
  const int total = 589824 + 172032 + 294912 + 294912;
  for (int j = blockIdx.x*blockDim.x + threadIdx.x; j < total; j += gridDim.x*blockDim.x) {
    if (j < 589824) {
      int n = j / 384, k = j % 384;
      int mat = n / 384;
      int np = n % 384;                        // (384 not pow2 -> %, not &)
      const float* W = (mat==0)?qw:(mat==1)?kw:(mat==2)?vw:gw;
      wqt[(size_t)n*384 + k] = __float2bfloat16(W[(size_t)k*384 + np]);
    } else if (j < 589824 + 172032) {
      int jj = j - 589824;
      int o = jj / 448, k = jj % 448;
      int kap = k >> 6, i = k & 63;
      cwt[(size_t)o*448 + k] = __float2bfloat16(cw[((size_t)o*64 + i)*7 + kap]);
    } else if (j < 589824 + 172032 + 294912) {
      int jj = j - (589824 + 172032);
      int n = jj / 384, k = jj % 384;
      w1t[(size_t)n*384 + k] = __float2bfloat16(w1[(size_t)k*768 + n]);
    } else {
      int jj = j - (589824 + 172032 + 294912);
      int n = jj / 768, k = jj % 768;
      w2t[(size_t)n*768 + k] = __float2bfloat16(w2[(size_t)k*384 + n]);
    }
  }
}

__global__ void k_prep_lam(const float* __restrict__ decay, float* __restrict__ lam) {
  __shared__ float red[6];
  int t = threadIdx.x; // 384 threads
  float v = sigf(decay[t]);
  for (int off = 32; off; off >>= 1) v += __shfl_xor(v, off, 64);
  if ((t & 63) == 0) red[t >> 6] = v;
  __syncthreads();
  if (t == 0) {
    float s = 0.f;
    for (int i = 0; i < 6; ++i) s += red[i];
    lam[0] = s * (1.f/384.f);
  }
}

// ---------------- grouped conv (k=7, groups=6) + silu -> xc bf16 ----------------
__global__ __launch_bounds__(256) void k_conv(const float* __restrict__ x, const float* __restrict__ cb,
                                              const bf16* __restrict__ cwt, bf16* __restrict__ xc) {
  int id = blockIdx.x;             // 1536 = 8 b * 32 st * 6 g
  int g = id % 6, st = (id/6) & 31, b = id / 192;
  int s0 = st * 128;
  __shared__ u16 xls[134*72];
  __shared__ u16 wls[64*456];
  int tid = threadIdx.x;
  for (int r0 = 0; r0 < 144; r0 += 16) {
    int row = r0 + (tid >> 4);
    if (row < 134) {
      int col = (tid & 15) * 4;
      int s = s0 - 3 + row;
      float4 v = make_float4(0.f,0.f,0.f,0.f);
      if (s >= 0 && s < SEQL)
        v = *reinterpret_cast<const float4*>(x + ((size_t)(b*SEQL + s))*DIMD + g*64 + col);
      u16* dst = &xls[row*72 + col];
      bf16 t0 = __float2bfloat16(v.x); dst[0] = *reinterpret_cast<u16*>(&t0);
      bf16 t1 = __float2bfloat16(v.y); dst[1] = *reinterpret_cast<u16*>(&t1);
      bf16 t2 = __float2bfloat16(v.z); dst[2] = *reinterpret_cast<u16*>(&t2);
      bf16 t3 = __float2bfloat16(v.w); dst[3] = *reinterpret_cast<u16*>(&t3);
    }
  }
  for (int i0 = 0; i0 < 28672; i0 += 1024) {
    int i = i0 + tid*4;
    int o = i / 448, k = i % 448;
    *reinterpret_cast<uint2*>(&wls[o*456 + k]) =
      *reinterpret_cast<const uint2*>(cwt + ((size_t)(g*64 + o))*448 + k);
  }
  __syncthreads();
  int w = tid >> 6, l = tid & 63, l15 = l & 15, lh = l >> 4;
  f32x4 zz = {0.f,0.f,0.f,0.f};
  f32x4 acc[2][4];
  for (int i=0;i<2;++i) for (int jn=0;jn<4;++jn) acc[i][jn]=zz;
  for (int kap = 0; kap < 7; ++kap) {
#pragma unroll
    for (int ic = 0; ic < 2; ++ic) {
      s16x8 a0 = *reinterpret_cast<const s16x8*>(&xls[(w*32 +  0 + l15 + kap)*72 + ic*32 + lh*8]);
      s16x8 a1 = *reinterpret_cast<const s16x8*>(&xls[(w*32 + 16 + l15 + kap)*72 + ic*32 + lh*8]);
#pragma unroll
      for (int nf = 0; nf < 4; ++nf) {
        s16x8 bfr = *reinterpret_cast<const s16x8*>(&wls[(nf*16 + l15)*456 + kap*64 + ic*32 + lh*8]);
        acc[0][nf] = __builtin_amdgcn_mfma_f32_16x16x32_bf16(a0, bfr, acc[0][nf], 0,0,0);
        acc[1][nf] = __builtin_amdgcn_mfma_f32_16x16x32_bf16(a1, bfr, acc[1][nf], 0,0,0);
      }
    }
  }
#pragma unroll
  for (int nf = 0; nf < 4; ++nf) {
    int ch = g*64 + nf*16 + l15;
    float bias = cb[ch];
#pragma unroll
    for (int mf = 0; mf < 2; ++mf) {
#pragma unroll
      for (int r = 0; r < 4; ++r) {
        int m = w*32 + mf*16 + lh*4 + r;
        float v = acc[mf][nf][r] + bias;
        v = v * sigf(v);
        xc[((size_t)(b*SEQL + s0 + m))*DIMD + ch] = __float2bfloat16(v);
      }
    }
  }
}

// ---------------- fused QKVG GEMM (R16): full-kc B prefetch + A stage-ahead dbuf -------------
// B-frags for kc are fully register-resident (loaded during kc-1, completed by the barrier);
// kc+1's B-loads are issued with the A-stage, so MFMAs never wait on B.
__global__ __launch_bounds__(256) void k_qkvg(const bf16* __restrict__ xc, const bf16* __restrict__ wt,
    const float* __restrict__ qb, const float* __restrict__ kb,
    const float* __restrict__ vb, const float* __restrict__ gb,
    bf16* __restrict__ qout, bf16* __restrict__ uout) {
  int raw = blockIdx.x;                       // 3072
  int vv = (raw & 7)*384 + (raw >> 3);        // XCD swizzle
  int mt = vv / 12, ct = vv % 12;
  int m0 = mt*128, c0 = ct*32;
  __shared__ __align__(16) u16 smem[16384];   // 32KB dbuf 2x[128][64] / exchange overlay
  int tid = threadIdx.x, w = tid >> 6, l = tid & 63, l15 = l & 15, lh = l >> 4;
  f32x4 zz = {0.f,0.f,0.f,0.f};
  f32x4 acc[8][2];
#pragma unroll
  for (int i=0;i<8;++i){ acc[i][0]=zz; acc[i][1]=zz; }
  const bf16* b0p = wt + ((size_t)(w*384 + c0 + l15))*384 + lh*8;
  const bf16* b1p = b0p + (size_t)16*384;
  // B regs: current kc fully resident (kk=0/1 x nf=0/1); next kc loading
  s16x8 bc00 = *reinterpret_cast<const s16x8*>(b0p);
  s16x8 bc01 = *reinterpret_cast<const s16x8*>(b1p);
  s16x8 bc10 = *reinterpret_cast<const s16x8*>(b0p + 32);
  s16x8 bc11 = *reinterpret_cast<const s16x8*>(b1p + 32);
  s16x8 bn00, bn01, bn10, bn11;
  // prologue: A tile 0 -> buf0
#pragma unroll
  for (int p = 0; p < 4; ++p) {
    int off16 = p*256 + tid;
    int row = off16 >> 3, slot = off16 & 7;
    int ss = slot ^ (row & 7);
    gl_lds16(xc + ((size_t)(m0+row))*DIMD + ss*8, (char*)smem + off16*16);
  }
  __syncthreads();
  for (int kc = 0; kc < 6; ++kc) {
    const u16* cur = smem + (kc & 1)*8192;
    // issue next-tile A stage + next-kc B loads BEFORE compute; drained by barrier after compute
    if (kc < 5) {
      char* nxt = (char*)(smem + ((kc & 1)^1)*8192);
#pragma unroll
      for (int p = 0; p < 4; ++p) {
        int off16 = p*256 + tid;
        int row = off16 >> 3, slot = off16 & 7;
        int ss = slot ^ (row & 7);
        gl_lds16(xc + ((size_t)(m0+row))*DIMD + (kc+1)*64 + ss*8, nxt + off16*16);
      }
      int nb = (kc+1)*64;
      bn00 = *reinterpret_cast<const s16x8*>(b0p + nb);
      bn01 = *reinterpret_cast<const s16x8*>(b1p + nb);
      bn10 = *reinterpret_cast<const s16x8*>(b0p + nb + 32);
      bn11 = *reinterpret_cast<const s16x8*>(b1p + nb + 32);
    }
#pragma unroll
    for (int kk = 0; kk < 2; ++kk) {
      s16x8 cur0 = kk ? bc10 : bc00;
      s16x8 cur1 = kk ? bc11 : bc01;
#pragma unroll
      for (int mf = 0; mf < 8; ++mf) {
        s16x8 af = *reinterpret_cast<const s16x8*>(
            &cur[(mf*16 + l15)*64 + (((kk*4 + lh) ^ (l15 & 7))*8)]);
        acc[mf][0] = __builtin_amdgcn_mfma_f32_16x16x32_bf16(af, cur0, acc[mf][0], 0,0,0);
        acc[mf][1] = __builtin_amdgcn_mfma_f32_16x16x32_bf16(af, cur1, acc[mf][1], 0,0,0);
      }
    }
    __syncthreads();   // drains vmcnt: next A tile + next B frags complete; cur consumed
    bc00 = bn00; bc01 = bn01; bc10 = bn10; bc11 = bn11;
  }
  const float* bp = (w==0)?qb:(w==1)?kb:(w==2)?vb:gb;
  float bias0 = bp[c0 + l15], bias1 = bp[c0 + 16 + l15];
  if (w == 0) {
#pragma unroll
    for (int mf=0;mf<8;++mf)
#pragma unroll
      for (int nf=0;nf<2;++nf) {
        float bs = nf ? bias1 : bias0;
#pragma unroll
        for (int r=0;r<4;++r) {
          int m = mf*16 + lh*4 + r, c = nf*16 + l15;
          qout[((size_t)(m0+m))*DIMD + c0 + c] = __float2bfloat16(acc[mf][nf][r] + bs);
        }
      }
  } else {
    u16* exm = smem + (size_t)(w-1)*(128*40);
#pragma unroll
    for (int mf=0;mf<8;++mf)
#pragma unroll
      for (int nf=0;nf<2;++nf) {
        float bs = nf ? bias1 : bias0;
#pragma unroll
        for (int r=0;r<4;++r) {
          int m = mf*16 + lh*4 + r, c = nf*16 + l15;
          bf16 t = __float2bfloat16(acc[mf][nf][r] + bs);
          exm[m*40 + c] = *reinterpret_cast<u16*>(&t);
        }
      }
  }
  __syncthreads();
#pragma unroll
  for (int p = 0; p < 16; ++p) {
    int idx = p*256 + tid;
    int m = idx >> 5, c = idx & 31;
    u16 kr = smem[0*(128*40) + m*40 + c];
    u16 vr = smem[1*(128*40) + m*40 + c];
    u16 gr = smem[2*(128*40) + m*40 + c];
    float kvv = __bfloat162float(*reinterpret_cast<bf16*>(&kr));
    float vvv = __bfloat162float(*reinterpret_cast<bf16*>(&vr));
    float gvv = __bfloat162float(*reinterpret_cast<bf16*>(&gr));
    uout[((size_t)(m0+m))*DIMD + c0 + c] = __float2bfloat16(vvv * sigf(gvv) * kvv);
  }
}

// ---------------- decayed cumsum + q*diag + LN1 -> h bf16 (48KB LDS, 3 blocks/CU) -------------
__global__ __launch_bounds__(384) void k_scan(const bf16* __restrict__ u, const bf16* __restrict__ q,
    const float* __restrict__ lam_p, const float* __restrict__ l1g, const float* __restrict__ l1b,
    bf16* __restrict__ h) {
  int b = blockIdx.x >> 5, c = blockIdx.x & 31; // 8 x 32
  int d = threadIdx.x;                          // 384
  float lam = lam_p[0];
  __shared__ float ols[32*384];                 // 48 KB
  __shared__ float lgs[384], lbs[384];
  lgs[d] = l1g[d]; lbs[d] = l1b[d];
  int s0 = c*128;
  size_t base = ((size_t)b*SEQL)*DIMD + d;
  float carry = 0.f;
  int sstart = s0 - 64; if (sstart < 0) sstart = 0;
  for (int s = sstart; s < s0; s += 8) {
    float uv[8];
#pragma unroll
    for (int j = 0; j < 8; ++j) uv[j] = __bfloat162float(u[base + (size_t)(s+j)*DIMD]);
#pragma unroll
    for (int j = 0; j < 8; ++j) carry = carry*lam + uv[j];
  }
  int w = d >> 6, lane = d & 63;
  for (int p = 0; p < 4; ++p) {
    int sb = s0 + p*32;
    __syncthreads();
    for (int it0 = 0; it0 < 32; it0 += 8) {
      float uv[8], qv[8];
#pragma unroll
      for (int j = 0; j < 8; ++j) uv[j] = __bfloat162float(u[base + (size_t)(sb+it0+j)*DIMD]);
#pragma unroll
      for (int j = 0; j < 8; ++j) qv[j] = __bfloat162float(q[base + (size_t)(sb+it0+j)*DIMD]);
#pragma unroll
      for (int j = 0; j < 8; ++j) {
        carry = carry*lam + uv[j];
        ols[(it0+j)*384 + d] = carry * qv[j];
      }
    }
    __syncthreads();
    for (int t = w; t < 32; t += 6) {
      float vv[6]; float s1 = 0.f, s2 = 0.f;
#pragma unroll
      for (int j = 0; j < 6; ++j) {
        vv[j] = ols[t*384 + j*64 + lane];
        s1 += vv[j]; s2 += vv[j]*vv[j];
      }
      for (int off = 32; off; off >>= 1) { s1 += __shfl_xor(s1, off, 64); s2 += __shfl_xor(s2, off, 64); }
      float mean = s1 * (1.f/384.f);
      float var = s2 * (1.f/384.f) - mean*mean;
      float rs = rsqrtf(var + 1e-5f);
      size_t rowo = ((size_t)(b*SEQL + sb + t))*DIMD;
#pragma unroll
      for (int j = 0; j < 6; ++j) {
        int dd = j*64 + lane;
        h[rowo + dd] = __float2bfloat16((vv[j]-mean)*rs*lgs[dd] + lbs[dd]);
      }
    }
  }
}

// ---------------- MLP GEMM1 + silu -> ai bf16 (T3 stage-ahead dbuf, BK=64) --------------
__global__ __launch_bounds__(512) void k_mlp1(const bf16* __restrict__ h, const bf16* __restrict__ w1t,
                                              const float* __restrict__ b1, bf16* __restrict__ ai) {
  int raw = blockIdx.x;                 // 1536
  int vv = (raw & 7)*192 + (raw >> 3);
  int mt = vv / 6, nt = vv % 6;
  int m0 = mt*128, n0 = nt*128;
  __shared__ __align__(16) u16 als[16384];   // 32KB = 2 x [128][64]
  int tid = threadIdx.x, w = tid >> 6, l = tid & 63, l15 = l & 15, lh = l >> 4;
  int wm = (w >> 2)*64, wn = (w & 3)*32;
  f32x4 zz = {0.f,0.f,0.f,0.f};
  f32x4 acc[4][2];
#pragma unroll
  for (int i=0;i<4;++i) for (int jn=0;jn<2;++jn) acc[i][jn]=zz;
  const bf16* bp0 = w1t + ((size_t)(n0 + wn + l15))*384 + lh*8;
  s16x8 bA[2], bB[2];
#pragma unroll
  for (int nf = 0; nf < 2; ++nf)
    bA[nf] = *reinterpret_cast<const s16x8*>(bp0 + (size_t)nf*16*384);
  // prologue: tile 0 -> buf0
#pragma unroll
  for (int p = 0; p < 2; ++p) {
    int off16 = p*512 + tid;
    int row = off16 >> 3, slot = off16 & 7;
    int ss = slot ^ (row & 7);
    gl_lds16(h + ((size_t)(m0+row))*DIMD + ss*8, (char*)als + off16*16);
  }
  __syncthreads();
  for (int kc = 0; kc < 6; ++kc) {
    const u16* cur = als + (kc & 1)*8192;
    if (kc < 5) {
      char* nxt = (char*)(als + ((kc & 1)^1)*8192);
#pragma unroll
      for (int p = 0; p < 2; ++p) {
        int off16 = p*512 + tid;
        int row = off16 >> 3, slot = off16 & 7;
        int ss = slot ^ (row & 7);
        gl_lds16(h + ((size_t)(m0+row))*DIMD + (kc+1)*64 + ss*8, nxt + off16*16);
      }
    }
#pragma unroll
    for (int kk = 0; kk < 2; ++kk) {
      int nko = (kk == 0) ? (kc*64 + 32) : ((kc < 5) ? (kc+1)*64 : -1);
      if (nko >= 0) {
        if (kk) {
#pragma unroll
          for (int nf = 0; nf < 2; ++nf)
            bA[nf] = *reinterpret_cast<const s16x8*>(bp0 + (size_t)nf*16*384 + nko);
        } else {
#pragma unroll
          for (int nf = 0; nf < 2; ++nf)
            bB[nf] = *reinterpret_cast<const s16x8*>(bp0 + (size_t)nf*16*384 + nko);
        }
      }
#pragma unroll
      for (int mf = 0; mf < 4; ++mf) {
        s16x8 af = *reinterpret_cast<const s16x8*>(
            &cur[(wm + mf*16 + l15)*64 + (((kk*4 + lh) ^ (l15 & 7))*8)]);
#pragma unroll
        for (int nf = 0; nf < 2; ++nf)
          acc[mf][nf] = __builtin_amdgcn_mfma_f32_16x16x32_bf16(
              af, kk ? bB[nf] : bA[nf], acc[mf][nf], 0,0,0);
      }
    }
    __syncthreads();
  }
  float bias[2];
#pragma unroll
  for (int nf = 0; nf < 2; ++nf) bias[nf] = b1[n0 + wn + nf*16 + l15];
#pragma unroll
  for (int mf = 0; mf < 4; ++mf)
#pragma unroll
    for (int nf = 0; nf < 2; ++nf)
#pragma unroll
      for (int r = 0; r < 4; ++r) {
        int m = wm + mf*16 + lh*4 + r, ch = n0 + wn + nf*16 + l15;
        float v = acc[mf][nf][r] + bias[nf];
        v = v * sigf(v);
        ai[(size_t)(m0+m)*768 + ch] = __float2bfloat16(v);
      }
}

// ---------------- fused MLP GEMM2 + bias + residual + LN2 -> out f32 (T3 dbuf) ----------
// 512 threads (8 waves), M=64/block, grid 512. Wave w owns cols [w*48, w*48+48).
__global__ __launch_bounds__(512) void k_mlp2ln(const bf16* __restrict__ ai, const bf16* __restrict__ w2t,
                                                const float* __restrict__ b2, const float* __restrict__ x,
                                                const float* __restrict__ l2g, const float* __restrict__ l2b,
                                                float* __restrict__ out) {
  int raw = blockIdx.x;                 // 512
  int mt = (raw & 7)*64 + (raw >> 3);   // XCD swizzle
  int m0 = mt*64;
  __shared__ __align__(16) u16 als[16384];    // 32KB = 2 x [64][128]
  __shared__ float pls[8][64][2];             // per-wave row partials (4KB)
  int tid = threadIdx.x, w = tid >> 6, l = tid & 63, l15 = l & 15, lh = l >> 4;
  int wn = w*48;
  f32x4 zz = {0.f,0.f,0.f,0.f};
  f32x4 acc[4][3];
#pragma unroll
  for (int i=0;i<4;++i)
#pragma unroll
    for (int jn=0;jn<3;++jn) acc[i][jn]=zz;
  const bf16* bp0 = w2t + ((size_t)(wn + l15))*768 + lh*8;
  s16x8 bA[3], bB[3];
#pragma unroll
  for (int nf = 0; nf < 3; ++nf)
    bA[nf] = *reinterpret_cast<const s16x8*>(bp0 + (size_t)nf*16*768);
  // prologue: tile 0 -> buf0
#pragma unroll
  for (int p = 0; p < 2; ++p) {
    int off16 = p*512 + tid;
    int row = off16 >> 4, slot = off16 & 15;
    int ss = slot ^ (row & 7);
    gl_lds16(ai + ((size_t)(m0+row))*768 + ss*8, (char*)als + off16*16);
  }
  __syncthreads();
  for (int kc = 0; kc < 6; ++kc) {
    const u16* cur = als + (kc & 1)*8192;
    if (kc < 5) {
      char* nxt = (char*)(als + ((kc & 1)^1)*8192);
#pragma unroll
      for (int p = 0; p < 2; ++p) {
        int off16 = p*512 + tid;
        int row = off16 >> 4, slot = off16 & 15;
        int ss = slot ^ (row & 7);
        gl_lds16(ai + ((size_t)(m0+row))*768 + (kc+1)*128 + ss*8, nxt + off16*16);
      }
    }
#pragma unroll
    for (int kk = 0; kk < 4; ++kk) {
      int nko = (kk < 3) ? (kc*128 + (kk+1)*32) : ((kc < 5) ? (kc+1)*128 : -1);
      if (nko >= 0) {
        if (kk & 1) {
#pragma unroll
          for (int nf = 0; nf < 3; ++nf)
            bA[nf] = *reinterpret_cast<const s16x8*>(bp0 + (size_t)nf*16*768 + nko);
        } else {
#pragma unroll
          for (int nf = 0; nf < 3; ++nf)
            bB[nf] = *reinterpret_cast<const s16x8*>(bp0 + (size_t)nf*16*768 + nko);
        }
      }
#pragma unroll
      for (int mf = 0; mf < 4; ++mf) {
        s16x8 af = *reinterpret_cast<const s16x8*>(
            &cur[(mf*16 + l15)*128 + (((kk*4 + lh) ^ (l15 & 7))*8)]);
#pragma unroll
        for (int nf = 0; nf < 3; ++nf)
          acc[mf][nf] = __builtin_amdgcn_mfma_f32_16x16x32_bf16(
              af, (kk & 1) ? bB[nf] : bA[nf], acc[mf][nf], 0,0,0);
      }
    }
    __syncthreads();
  }
  // epilogue: v = acc + b2 + x (in place), row stats, LN, store
  float bias[3];
#pragma unroll
  for (int nf = 0; nf < 3; ++nf) bias[nf] = b2[wn + nf*16 + l15];
#pragma unroll
  for (int mf = 0; mf < 4; ++mf) {
#pragma unroll
    for (int r = 0; r < 4; ++r) {
      int m = mf*16 + lh*4 + r;
      const float* xr = x + (size_t)(m0+m)*DIMD + wn + l15;
      float sa = 0.f, sb = 0.f;
#pragma unroll
      for (int nf = 0; nf < 3; ++nf) {
        float v = acc[mf][nf][r] + bias[nf] + xr[nf*16];
        acc[mf][nf][r] = v;
        sa += v; sb += v*v;
      }
#pragma unroll
      for (int off = 1; off < 16; off <<= 1) {
        sa += __shfl_xor(sa, off, 16);
        sb += __shfl_xor(sb, off, 16);
      }
      if (l15 == 0) { pls[w][m][0] = sa; pls[w][m][1] = sb; }
    }
  }
  __syncthreads();
  float lg[3], lb[3];
#pragma unroll
  for (int nf = 0; nf < 3; ++nf) { lg[nf] = l2g[wn + nf*16 + l15]; lb[nf] = l2b[wn + nf*16 + l15]; }
#pragma unroll
  for (int mf = 0; mf < 4; ++mf) {
#pragma unroll
    for (int r = 0; r < 4; ++r) {
      int m = mf*16 + lh*4 + r;
      float S1 = 0.f, S2 = 0.f;
#pragma unroll
      for (int ww = 0; ww < 8; ++ww) { S1 += pls[ww][m][0]; S2 += pls[ww][m][1]; }
      float mean = S1 * (1.f/384.f);
      float var = S2 * (1.f/384.f) - mean*mean;
      float rs = rsqrtf(var + 1e-5f);
      float* orow = out + (size_t)(m0+m)*DIMD + wn + l15;
#pragma unroll
      for (int nf = 0; nf < 3; ++nf)
        orow[nf*16] = (acc[mf][nf][r] - mean)*rs*lg[nf] + lb[nf];
    }
  }
}

extern "C" void kernel_launch(void* const* d_in, const int* in_sizes, int n_in,
                              void* d_out, int out_size, void* d_ws, size_t ws_size,
                              hipStream_t stream) {
  const float* x   = (const float*)d_in[0];
  const float* cw  = (const float*)d_in[1];
  const float* cb  = (const float*)d_in[2];
  const float* qw  = (const float*)d_in[3];
  const float* qb  = (const float*)d_in[4];
  const float* kw  = (const float*)d_in[5];
  const float* kb  = (const float*)d_in[6];
  const float* vw  = (const float*)d_in[7];
  const float* vb  = (const float*)d_in[8];
  const float* gw  = (const float*)d_in[9];
  const float* gb  = (const float*)d_in[10];
  const float* dec = (const float*)d_in[11];
  const float* l1g = (const float*)d_in[12];
  const float* l1b = (const float*)d_in[13];
  const float* w1  = (const float*)d_in[14];
  const float* b1  = (const float*)d_in[15];
  const float* w2  = (const float*)d_in[16];
  const float* b2  = (const float*)d_in[17];
  const float* l2g = (const float*)d_in[18];
  const float* l2b = (const float*)d_in[19];

  char* ws = (char*)d_ws;
  float* lam = (float*)(ws + OFF_LAM);
  bf16* wqt  = (bf16*)(ws + OFF_WQ);
  bf16* cwt  = (bf16*)(ws + OFF_CW);
  bf16* w1t  = (bf16*)(ws + OFF_W1T);
  bf16* w2t  = (bf16*)(ws + OFF_W2T);
  bf16* xc   = (bf16*)(ws + OFF_XC);
  bf16* q    = (bf16*)(ws + OFF_Q);
  bf16* u    = (bf16*)(ws + OFF_U);
  bf16* hbuf = (bf16*)(ws + OFF_H);
  bf16* ai   = (bf16*)(ws + OFF_AI);
  float* out = (float*)d_out;

  hipLaunchKernelGGL(k_prep_w,  dim3(1024), dim3(256), 0, stream, qw,kw,vw,gw,cw,w1,w2, wqt,cwt,w1t,w2t);
  hipLaunchKernelGGL(k_prep_lam,dim3(1),    dim3(384), 0, stream, dec, lam);
  hipLaunchKernelGGL(k_conv,    dim3(1536), dim3(256), 0, stream, x, cb, cwt, xc);
  hipLaunchKernelGGL(k_qkvg,    dim3(3072), dim3(256), 0, stream, xc, wqt, qb,kb,vb,gb, q, u);
  hipLaunchKernelGGL(k_scan,    dim3(256),  dim3(384), 0, stream, u, q, lam, l1g, l1b, hbuf);
  hipLaunchKernelGGL(k_mlp1,    dim3(1536), dim3(512), 0, stream, hbuf, w1t, b1, ai);
  hipLaunchKernelGGL(k_mlp2ln,  dim3(512),  dim3(512), 0, stream, ai, w2t, b2, x, l2g, l2b, out);
}

// Round 17
// 231.568 us; speedup vs baseline: 1.3978x; 1.0335x over previous
//
#include <hip/hip_runtime.h>
#include <hip/hip_bf16.h>

#define DIMD 384
#define SEQL 4096
#define NBATCH 8
#define NTOK (NBATCH*SEQL)

typedef float f32x4 __attribute__((ext_vector_type(4)));
typedef short s16x8 __attribute__((ext_vector_type(8)));
typedef unsigned short u16;
typedef __hip_bfloat16 bf16;

__device__ __forceinline__ float sigf(float x){ return 1.f/(1.f+__expf(-x)); }

// async global->LDS, 16B per lane. LDS dest must be wave-uniform base + lane*16.
typedef __attribute__((address_space(3))) void lds_void;
typedef const __attribute__((address_space(1))) void glb_void;
__device__ __forceinline__ void gl_lds16(const void* g, void* l) {
  __builtin_amdgcn_global_load_lds((glb_void*)g, (lds_void*)l, 16, 0, 0);
}

// ---------------- workspace layout (bytes) ----------------
#define OFF_LAM   0ul
#define OFF_WQ    4096ul                       // bf16 [1536][384]
#define OFF_CW    (OFF_WQ + 1179648ul)         // bf16 [384][448]
#define OFF_W1T   (OFF_CW + 344064ul)          // bf16 [768][384]
#define OFF_W2T   (OFF_W1T + 589824ul)         // bf16 [384][768]
#define OFF_XC    4194304ul                    // bf16 [32768][384]
#define OFF_Q     (OFF_XC + 25165824ul)        // bf16 [32768][384]
#define OFF_U     (OFF_XC + 50331648ul)        // bf16 [32768][384]
#define OFF_AI    OFF_U                        // bf16 [32768][768] (reuse after u dead)
#define OFF_H     (OFF_U + 50331648ul)         // bf16 [32768][384]
// total = 130,023,424 bytes

// ---------------- prep: weight transposes to [n][k] bf16 ----------------
__global__ void k_prep_w(const float* __restrict__ qw, const float* __restrict__ kw,
                         const float* __restrict__ vw, const float* __restrict__ gw,
                         const float* __restrict__ cw, const float* __restrict__ w1,
                         const float* __restrict__ w2,
                         bf16* __restrict__ wqt, bf16* __restrict__ cwt,
                         bf16* __restrict__ w1t, bf16* __restrict__ w2t) {
  const int total = 589824 + 172032 + 294912 + 294912;
  for (int j = blockIdx.x*blockDim.x + threadIdx.x; j < total; j += gridDim.x*blockDim.x) {
    if (j < 589824) {
      int n = j / 384, k = j % 384;
      int mat = n / 384;
      int np = n % 384;                        // (384 not pow2 -> %, not &)
      const float* W = (mat==0)?qw:(mat==1)?kw:(mat==2)?vw:gw;
      wqt[(size_t)n*384 + k] = __float2bfloat16(W[(size_t)k*384 + np]);
    } else if (j < 589824 + 172032) {
      int jj = j - 589824;
      int o = jj / 448, k = jj % 448;
      int kap = k >> 6, i = k & 63;
      cwt[(size_t)o*448 + k] = __float2bfloat16(cw[((size_t)o*64 + i)*7 + kap]);
    } else if (j < 589824 + 172032 + 294912) {
      int jj = j - (589824 + 172032);
      int n = jj / 384, k = jj % 384;
      w1t[(size_t)n*384 + k] = __float2bfloat16(w1[(size_t)k*768 + n]);
    } else {
      int jj = j - (589824 + 172032 + 294912);
      int n = jj / 768, k = jj % 768;
      w2t[(size_t)n*768 + k] = __float2bfloat16(w2[(size_t)k*384 + n]);
    }
  }
}

__global__ void k_prep_lam(const float* __restrict__ decay, float* __restrict__ lam) {
  __shared__ float red[6];
  int t = threadIdx.x; // 384 threads
  float v = sigf(decay[t]);
  for (int off = 32; off; off >>= 1) v += __shfl_xor(v, off, 64);
  if ((t & 63) == 0) red[t >> 6] = v;
  __syncthreads();
  if (t == 0) {
    float s = 0.f;
    for (int i = 0; i < 6; ++i) s += red[i];
    lam[0] = s * (1.f/384.f);
  }
}

// ---------------- grouped conv (k=7, groups=6) + silu -> xc bf16 ----------------
__global__ __launch_bounds__(256) void k_conv(const float* __restrict__ x, const float* __restrict__ cb,
                                              const bf16* __restrict__ cwt, bf16* __restrict__ xc) {
  int id = blockIdx.x;             // 1536 = 8 b * 32 st * 6 g
  int g = id % 6, st = (id/6) & 31, b = id / 192;
  int s0 = st * 128;
  __shared__ u16 xls[134*72];
  __shared__ u16 wls[64*456];
  int tid = threadIdx.x;
  for (int r0 = 0; r0 < 144; r0 += 16) {
    int row = r0 + (tid >> 4);
    if (row < 134) {
      int col = (tid & 15) * 4;
      int s = s0 - 3 + row;
      float4 v = make_float4(0.f,0.f,0.f,0.f);
      if (s >= 0 && s < SEQL)
        v = *reinterpret_cast<const float4*>(x + ((size_t)(b*SEQL + s))*DIMD + g*64 + col);
      u16* dst = &xls[row*72 + col];
      bf16 t0 = __float2bfloat16(v.x); dst[0] = *reinterpret_cast<u16*>(&t0);
      bf16 t1 = __float2bfloat16(v.y); dst[1] = *reinterpret_cast<u16*>(&t1);
      bf16 t2 = __float2bfloat16(v.z); dst[2] = *reinterpret_cast<u16*>(&t2);
      bf16 t3 = __float2bfloat16(v.w); dst[3] = *reinterpret_cast<u16*>(&t3);
    }
  }
  for (int i0 = 0; i0 < 28672; i0 += 1024) {
    int i = i0 + tid*4;
    int o = i / 448, k = i % 448;
    *reinterpret_cast<uint2*>(&wls[o*456 + k]) =
      *reinterpret_cast<const uint2*>(cwt + ((size_t)(g*64 + o))*448 + k);
  }
  __syncthreads();
  int w = tid >> 6, l = tid & 63, l15 = l & 15, lh = l >> 4;
  f32x4 zz = {0.f,0.f,0.f,0.f};
  f32x4 acc[2][4];
  for (int i=0;i<2;++i) for (int jn=0;jn<4;++jn) acc[i][jn]=zz;
  for (int kap = 0; kap < 7; ++kap) {
#pragma unroll
    for (int ic = 0; ic < 2; ++ic) {
      s16x8 a0 = *reinterpret_cast<const s16x8*>(&xls[(w*32 +  0 + l15 + kap)*72 + ic*32 + lh*8]);
      s16x8 a1 = *reinterpret_cast<const s16x8*>(&xls[(w*32 + 16 + l15 + kap)*72 + ic*32 + lh*8]);
#pragma unroll
      for (int nf = 0; nf < 4; ++nf) {
        s16x8 bfr = *reinterpret_cast<const s16x8*>(&wls[(nf*16 + l15)*456 + kap*64 + ic*32 + lh*8]);
        acc[0][nf] = __builtin_amdgcn_mfma_f32_16x16x32_bf16(a0, bfr, acc[0][nf], 0,0,0);
        acc[1][nf] = __builtin_amdgcn_mfma_f32_16x16x32_bf16(a1, bfr, acc[1][nf], 0,0,0);
      }
    }
  }
#pragma unroll
  for (int nf = 0; nf < 4; ++nf) {
    int ch = g*64 + nf*16 + l15;
    float bias = cb[ch];
#pragma unroll
    for (int mf = 0; mf < 2; ++mf) {
#pragma unroll
      for (int r = 0; r < 4; ++r) {
        int m = w*32 + mf*16 + lh*4 + r;
        float v = acc[mf][nf][r] + bias;
        v = v * sigf(v);
        xc[((size_t)(b*SEQL + s0 + m))*DIMD + ch] = __float2bfloat16(v);
      }
    }
  }
}

// ---------------- fused QKVG GEMM (R17): 8 waves, wave owns (matrix, 16-col half) ------------
// Same 128x32x4-matrix block tile; 512 threads double wave residency (~24 waves/CU static).
// A stage-ahead dbuf (BK=64) + full-kc B prefetch retained.
__global__ __launch_bounds__(512) void k_qkvg(const bf16* __restrict__ xc, const bf16* __restrict__ wt,
    const float* __restrict__ qb, const float* __restrict__ kb,
    const float* __restrict__ vb, const float* __restrict__ gb,
    bf16* __restrict__ qout, bf16* __restrict__ uout) {
  int raw = blockIdx.x;                       // 3072
  int vv = (raw & 7)*384 + (raw >> 3);        // XCD swizzle
  int mt = vv / 12, ct = vv % 12;
  int m0 = mt*128, c0 = ct*32;
  __shared__ __align__(16) u16 smem[16384];   // 32KB dbuf 2x[128][64] / exchange overlay
  int tid = threadIdx.x, w = tid >> 6, l = tid & 63, l15 = l & 15, lh = l >> 4;
  int mat = w >> 1, ch0 = (w & 1)*16;         // wave's matrix + col-half
  f32x4 zz = {0.f,0.f,0.f,0.f};
  f32x4 acc[8];
#pragma unroll
  for (int i=0;i<8;++i) acc[i]=zz;
  const bf16* bp = wt + ((size_t)(mat*384 + c0 + ch0 + l15))*384 + lh*8;
  // B regs: current kc fully resident (kk=0/1); next kc loading
  s16x8 bc0 = *reinterpret_cast<const s16x8*>(bp);
  s16x8 bc1 = *reinterpret_cast<const s16x8*>(bp + 32);
  s16x8 bn0, bn1;
  // prologue: A tile 0 -> buf0 (1024 chunks of 16B, 512 threads)
#pragma unroll
  for (int p = 0; p < 2; ++p) {
    int off16 = p*512 + tid;
    int row = off16 >> 3, slot = off16 & 7;
    int ss = slot ^ (row & 7);
    gl_lds16(xc + ((size_t)(m0+row))*DIMD + ss*8, (char*)smem + off16*16);
  }
  __syncthreads();
  for (int kc = 0; kc < 6; ++kc) {
    const u16* cur = smem + (kc & 1)*8192;
    if (kc < 5) {
      char* nxt = (char*)(smem + ((kc & 1)^1)*8192);
#pragma unroll
      for (int p = 0; p < 2; ++p) {
        int off16 = p*512 + tid;
        int row = off16 >> 3, slot = off16 & 7;
        int ss = slot ^ (row & 7);
        gl_lds16(xc + ((size_t)(m0+row))*DIMD + (kc+1)*64 + ss*8, nxt + off16*16);
      }
      int nb = (kc+1)*64;
      bn0 = *reinterpret_cast<const s16x8*>(bp + nb);
      bn1 = *reinterpret_cast<const s16x8*>(bp + nb + 32);
    }
#pragma unroll
    for (int kk = 0; kk < 2; ++kk) {
      s16x8 curb = kk ? bc1 : bc0;
#pragma unroll
      for (int mf = 0; mf < 8; ++mf) {
        s16x8 af = *reinterpret_cast<const s16x8*>(
            &cur[(mf*16 + l15)*64 + (((kk*4 + lh) ^ (l15 & 7))*8)]);
        acc[mf] = __builtin_amdgcn_mfma_f32_16x16x32_bf16(af, curb, acc[mf], 0,0,0);
      }
    }
    __syncthreads();   // drains vmcnt: next A tile + next B frags complete; cur consumed
    bc0 = bn0; bc1 = bn1;
  }
  const float* bpv = (mat==0)?qb:(mat==1)?kb:(mat==2)?vb:gb;
  float bias = bpv[c0 + ch0 + l15];
  if (mat == 0) {
#pragma unroll
    for (int mf=0;mf<8;++mf)
#pragma unroll
      for (int r=0;r<4;++r) {
        int m = mf*16 + lh*4 + r, c = ch0 + l15;
        qout[((size_t)(m0+m))*DIMD + c0 + c] = __float2bfloat16(acc[mf][r] + bias);
      }
  } else {
    u16* exm = smem + (size_t)(mat-1)*(128*40);
#pragma unroll
    for (int mf=0;mf<8;++mf)
#pragma unroll
      for (int r=0;r<4;++r) {
        int m = mf*16 + lh*4 + r, c = ch0 + l15;
        bf16 t = __float2bfloat16(acc[mf][r] + bias);
        exm[m*40 + c] = *reinterpret_cast<u16*>(&t);
      }
  }
  __syncthreads();
#pragma unroll
  for (int p = 0; p < 8; ++p) {
    int idx = p*512 + tid;
    int m = idx >> 5, c = idx & 31;
    u16 kr = smem[0*(128*40) + m*40 + c];
    u16 vr = smem[1*(128*40) + m*40 + c];
    u16 gr = smem[2*(128*40) + m*40 + c];
    float kvv = __bfloat162float(*reinterpret_cast<bf16*>(&kr));
    float vvv = __bfloat162float(*reinterpret_cast<bf16*>(&vr));
    float gvv = __bfloat162float(*reinterpret_cast<bf16*>(&gr));
    uout[((size_t)(m0+m))*DIMD + c0 + c] = __float2bfloat16(vvv * sigf(gvv) * kvv);
  }
}

// ---------------- decayed cumsum + q*diag + LN1 -> h bf16 (48KB LDS, 3 blocks/CU) -------------
__global__ __launch_bounds__(384) void k_scan(const bf16* __restrict__ u, const bf16* __restrict__ q,
    const float* __restrict__ lam_p, const float* __restrict__ l1g, const float* __restrict__ l1b,
    bf16* __restrict__ h) {
  int b = blockIdx.x >> 5, c = blockIdx.x & 31; // 8 x 32
  int d = threadIdx.x;                          // 384
  float lam = lam_p[0];
  __shared__ float ols[32*384];                 // 48 KB
  __shared__ float lgs[384], lbs[384];
  lgs[d] = l1g[d]; lbs[d] = l1b[d];
  int s0 = c*128;
  size_t base = ((size_t)b*SEQL)*DIMD + d;
  float carry = 0.f;
  int sstart = s0 - 64; if (sstart < 0) sstart = 0;
  for (int s = sstart; s < s0; s += 8) {
    float uv[8];
#pragma unroll
    for (int j = 0; j < 8; ++j) uv[j] = __bfloat162float(u[base + (size_t)(s+j)*DIMD]);
#pragma unroll
    for (int j = 0; j < 8; ++j) carry = carry*lam + uv[j];
  }
  int w = d >> 6, lane = d & 63;
  for (int p = 0; p < 4; ++p) {
    int sb = s0 + p*32;
    __syncthreads();
    for (int it0 = 0; it0 < 32; it0 += 8) {
      float uv[8], qv[8];
#pragma unroll
      for (int j = 0; j < 8; ++j) uv[j] = __bfloat162float(u[base + (size_t)(sb+it0+j)*DIMD]);
#pragma unroll
      for (int j = 0; j < 8; ++j) qv[j] = __bfloat162float(q[base + (size_t)(sb+it0+j)*DIMD]);
#pragma unroll
      for (int j = 0; j < 8; ++j) {
        carry = carry*lam + uv[j];
        ols[(it0+j)*384 + d] = carry * qv[j];
      }
    }
    __syncthreads();
    for (int t = w; t < 32; t += 6) {
      float vv[6]; float s1 = 0.f, s2 = 0.f;
#pragma unroll
      for (int j = 0; j < 6; ++j) {
        vv[j] = ols[t*384 + j*64 + lane];
        s1 += vv[j]; s2 += vv[j]*vv[j];
      }
      for (int off = 32; off; off >>= 1) { s1 += __shfl_xor(s1, off, 64); s2 += __shfl_xor(s2, off, 64); }
      float mean = s1 * (1.f/384.f);
      float var = s2 * (1.f/384.f) - mean*mean;
      float rs = rsqrtf(var + 1e-5f);
      size_t rowo = ((size_t)(b*SEQL + sb + t))*DIMD;
#pragma unroll
      for (int j = 0; j < 6; ++j) {
        int dd = j*64 + lane;
        h[rowo + dd] = __float2bfloat16((vv[j]-mean)*rs*lgs[dd] + lbs[dd]);
      }
    }
  }
}

// ---------------- MLP GEMM1 + silu -> ai bf16 (T3 stage-ahead dbuf, BK=64) --------------
__global__ __launch_bounds__(512) void k_mlp1(const bf16* __restrict__ h, const bf16* __restrict__ w1t,
                                              const float* __restrict__ b1, bf16* __restrict__ ai) {
  int raw = blockIdx.x;                 // 1536
  int vv = (raw & 7)*192 + (raw >> 3);
  int mt = vv / 6, nt = vv % 6;
  int m0 = mt*128, n0 = nt*128;
  __shared__ __align__(16) u16 als[16384];   // 32KB = 2 x [128][64]
  int tid = threadIdx.x, w = tid >> 6, l = tid & 63, l15 = l & 15, lh = l >> 4;
  int wm = (w >> 2)*64, wn = (w & 3)*32;
  f32x4 zz = {0.f,0.f,0.f,0.f};
  f32x4 acc[4][2];
#pragma unroll
  for (int i=0;i<4;++i) for (int jn=0;jn<2;++jn) acc[i][jn]=zz;
  const bf16* bp0 = w1t + ((size_t)(n0 + wn + l15))*384 + lh*8;
  s16x8 bA[2], bB[2];
#pragma unroll
  for (int nf = 0; nf < 2; ++nf)
    bA[nf] = *reinterpret_cast<const s16x8*>(bp0 + (size_t)nf*16*384);
  // prologue: tile 0 -> buf0
#pragma unroll
  for (int p = 0; p < 2; ++p) {
    int off16 = p*512 + tid;
    int row = off16 >> 3, slot = off16 & 7;
    int ss = slot ^ (row & 7);
    gl_lds16(h + ((size_t)(m0+row))*DIMD + ss*8, (char*)als + off16*16);
  }
  __syncthreads();
  for (int kc = 0; kc < 6; ++kc) {
    const u16* cur = als + (kc & 1)*8192;
    if (kc < 5) {
      char* nxt = (char*)(als + ((kc & 1)^1)*8192);
#pragma unroll
      for (int p = 0; p < 2; ++p) {
        int off16 = p*512 + tid;
        int row = off16 >> 3, slot = off16 & 7;
        int ss = slot ^ (row & 7);
        gl_lds16(h + ((size_t)(m0+row))*DIMD + (kc+1)*64 + ss*8, nxt + off16*16);
      }
    }
#pragma unroll
    for (int kk = 0; kk < 2; ++kk) {
      int nko = (kk == 0) ? (kc*64 + 32) : ((kc < 5) ? (kc+1)*64 : -1);
      if (nko >= 0) {
        if (kk) {
#pragma unroll
          for (int nf = 0; nf < 2; ++nf)
            bA[nf] = *reinterpret_cast<const s16x8*>(bp0 + (size_t)nf*16*384 + nko);
        } else {
#pragma unroll
          for (int nf = 0; nf < 2; ++nf)
            bB[nf] = *reinterpret_cast<const s16x8*>(bp0 + (size_t)nf*16*384 + nko);
        }
      }
#pragma unroll
      for (int mf = 0; mf < 4; ++mf) {
        s16x8 af = *reinterpret_cast<const s16x8*>(
            &cur[(wm + mf*16 + l15)*64 + (((kk*4 + lh) ^ (l15 & 7))*8)]);
#pragma unroll
        for (int nf = 0; nf < 2; ++nf)
          acc[mf][nf] = __builtin_amdgcn_mfma_f32_16x16x32_bf16(
              af, kk ? bB[nf] : bA[nf], acc[mf][nf], 0,0,0);
      }
    }
    __syncthreads();
  }
  float bias[2];
#pragma unroll
  for (int nf = 0; nf < 2; ++nf) bias[nf] = b1[n0 + wn + nf*16 + l15];
#pragma unroll
  for (int mf = 0; mf < 4; ++mf)
#pragma unroll
    for (int nf = 0; nf < 2; ++nf)
#pragma unroll
      for (int r = 0; r < 4; ++r) {
        int m = wm + mf*16 + lh*4 + r, ch = n0 + wn + nf*16 + l15;
        float v = acc[mf][nf][r] + bias[nf];
        v = v * sigf(v);
        ai[(size_t)(m0+m)*768 + ch] = __float2bfloat16(v);
      }
}

// ---------------- fused MLP GEMM2 + bias + residual + LN2 -> out f32 (T3 dbuf) ----------
// 512 threads (8 waves), M=64/block, grid 512. Wave w owns cols [w*48, w*48+48).
__global__ __launch_bounds__(512) void k_mlp2ln(const bf16* __restrict__ ai, const bf16* __restrict__ w2t,
                                                const float* __restrict__ b2, const float* __restrict__ x,
                                                const float* __restrict__ l2g, const float* __restrict__ l2b,
                                                float* __restrict__ out) {
  int raw = blockIdx.x;                 // 512
  int mt = (raw & 7)*64 + (raw >> 3);   // XCD swizzle
  int m0 = mt*64;
  __shared__ __align__(16) u16 als[16384];    // 32KB = 2 x [64][128]
  __shared__ float pls[8][64][2];             // per-wave row partials (4KB)
  int tid = threadIdx.x, w = tid >> 6, l = tid & 63, l15 = l & 15, lh = l >> 4;
  int wn = w*48;
  f32x4 zz = {0.f,0.f,0.f,0.f};
  f32x4 acc[4][3];
#pragma unroll
  for (int i=0;i<4;++i)
#pragma unroll
    for (int jn=0;jn<3;++jn) acc[i][jn]=zz;
  const bf16* bp0 = w2t + ((size_t)(wn + l15))*768 + lh*8;
  s16x8 bA[3], bB[3];
#pragma unroll
  for (int nf = 0; nf < 3; ++nf)
    bA[nf] = *reinterpret_cast<const s16x8*>(bp0 + (size_t)nf*16*768);
  // prologue: tile 0 -> buf0
#pragma unroll
  for (int p = 0; p < 2; ++p) {
    int off16 = p*512 + tid;
    int row = off16 >> 4, slot = off16 & 15;
    int ss = slot ^ (row & 7);
    gl_lds16(ai + ((size_t)(m0+row))*768 + ss*8, (char*)als + off16*16);
  }
  __syncthreads();
  for (int kc = 0; kc < 6; ++kc) {
    const u16* cur = als + (kc & 1)*8192;
    if (kc < 5) {
      char* nxt = (char*)(als + ((kc & 1)^1)*8192);
#pragma unroll
      for (int p = 0; p < 2; ++p) {
        int off16 = p*512 + tid;
        int row = off16 >> 4, slot = off16 & 15;
        int ss = slot ^ (row & 7);
        gl_lds16(ai + ((size_t)(m0+row))*768 + (kc+1)*128 + ss*8, nxt + off16*16);
      }
    }
#pragma unroll
    for (int kk = 0; kk < 4; ++kk) {
      int nko = (kk < 3) ? (kc*128 + (kk+1)*32) : ((kc < 5) ? (kc+1)*128 : -1);
      if (nko >= 0) {
        if (kk & 1) {
#pragma unroll
          for (int nf = 0; nf < 3; ++nf)
            bA[nf] = *reinterpret_cast<const s16x8*>(bp0 + (size_t)nf*16*768 + nko);
        } else {
#pragma unroll
          for (int nf = 0; nf < 3; ++nf)
            bB[nf] = *reinterpret_cast<const s16x8*>(bp0 + (size_t)nf*16*768 + nko);
        }
      }
#pragma unroll
      for (int mf = 0; mf < 4; ++mf) {
        s16x8 af = *reinterpret_cast<const s16x8*>(
            &cur[(mf*16 + l15)*128 + (((kk*4 + lh) ^ (l15 & 7))*8)]);
#pragma unroll
        for (int nf = 0; nf < 3; ++nf)
          acc[mf][nf] = __builtin_amdgcn_mfma_f32_16x16x32_bf16(
              af, (kk & 1) ? bB[nf] : bA[nf], acc[mf][nf], 0,0,0);
      }
    }
    __syncthreads();
  }
  // epilogue: v = acc + b2 + x (in place), row stats, LN, store
  float bias[3];
#pragma unroll
  for (int nf = 0; nf < 3; ++nf) bias[nf] = b2[wn + nf*16 + l15];
#pragma unroll
  for (int mf = 0; mf < 4; ++mf) {
#pragma unroll
    for (int r = 0; r < 4; ++r) {
      int m = mf*16 + lh*4 + r;
      const float* xr = x + (size_t)(m0+m)*DIMD + wn + l15;
      float sa = 0.f, sb = 0.f;
#pragma unroll
      for (int nf = 0; nf < 3; ++nf) {
        float v = acc[mf][nf][r] + bias[nf] + xr[nf*16];
        acc[mf][nf][r] = v;
        sa += v; sb += v*v;
      }
#pragma unroll
      for (int off = 1; off < 16; off <<= 1) {
        sa += __shfl_xor(sa, off, 16);
        sb += __shfl_xor(sb, off, 16);
      }
      if (l15 == 0) { pls[w][m][0] = sa; pls[w][m][1] = sb; }
    }
  }
  __syncthreads();
  float lg[3], lb[3];
#pragma unroll
  for (int nf = 0; nf < 3; ++nf) { lg[nf] = l2g[wn + nf*16 + l15]; lb[nf] = l2b[wn + nf*16 + l15]; }
#pragma unroll
  for (int mf = 0; mf < 4; ++mf) {
#pragma unroll
    for (int r = 0; r < 4; ++r) {
      int m = mf*16 + lh*4 + r;
      float S1 = 0.f, S2 = 0.f;
#pragma unroll
      for (int ww = 0; ww < 8; ++ww) { S1 += pls[ww][m][0]; S2 += pls[ww][m][1]; }
      float mean = S1 * (1.f/384.f);
      float var = S2 * (1.f/384.f) - mean*mean;
      float rs = rsqrtf(var + 1e-5f);
      float* orow = out + (size_t)(m0+m)*DIMD + wn + l15;
#pragma unroll
      for (int nf = 0; nf < 3; ++nf)
        orow[nf*16] = (acc[mf][nf][r] - mean)*rs*lg[nf] + lb[nf];
    }
  }
}

extern "C" void kernel_launch(void* const* d_in, const int* in_sizes, int n_in,
                              void* d_out, int out_size, void* d_ws, size_t ws_size,
                              hipStream_t stream) {
  const float* x   = (const float*)d_in[0];
  const float* cw  = (const float*)d_in[1];
  const float* cb  = (const float*)d_in[2];
  const float* qw  = (const float*)d_in[3];
  const float* qb  = (const float*)d_in[4];
  const float* kw  = (const float*)d_in[5];
  const float* kb  = (const float*)d_in[6];
  const float* vw  = (const float*)d_in[7];
  const float* vb  = (const float*)d_in[8];
  const float* gw  = (const float*)d_in[9];
  const float* gb  = (const float*)d_in[10];
  const float* dec = (const float*)d_in[11];
  const float* l1g = (const float*)d_in[12];
  const float* l1b = (const float*)d_in[13];
  const float* w1  = (const float*)d_in[14];
  const float* b1  = (const float*)d_in[15];
  const float* w2  = (const float*)d_in[16];
  const float* b2  = (const float*)d_in[17];
  const float* l2g = (const float*)d_in[18];
  const float* l2b = (const float*)d_in[19];

  char* ws = (char*)d_ws;
  float* lam = (float*)(ws + OFF_LAM);
  bf16* wqt  = (bf16*)(ws + OFF_WQ);
  bf16* cwt  = (bf16*)(ws + OFF_CW);
  bf16* w1t  = (bf16*)(ws + OFF_W1T);
  bf16* w2t  = (bf16*)(ws + OFF_W2T);
  bf16* xc   = (bf16*)(ws + OFF_XC);
  bf16* q    = (bf16*)(ws + OFF_Q);
  bf16* u    = (bf16*)(ws + OFF_U);
  bf16* hbuf = (bf16*)(ws + OFF_H);
  bf16* ai   = (bf16*)(ws + OFF_AI);
  float* out = (float*)d_out;

  hipLaunchKernelGGL(k_prep_w,  dim3(1024), dim3(256), 0, stream, qw,kw,vw,gw,cw,w1,w2, wqt,cwt,w1t,w2t);
  hipLaunchKernelGGL(k_prep_lam,dim3(1),    dim3(384), 0, stream, dec, lam);
  hipLaunchKernelGGL(k_conv,    dim3(1536), dim3(256), 0, stream, x, cb, cwt, xc);
  hipLaunchKernelGGL(k_qkvg,    dim3(3072), dim3(512), 0, stream, xc, wqt, qb,kb,vb,gb, q, u);
  hipLaunchKernelGGL(k_scan,    dim3(256),  dim3(384), 0, stream, u, q, lam, l1g, l1b, hbuf);
  hipLaunchKernelGGL(k_mlp1,    dim3(1536), dim3(512), 0, stream, hbuf, w1t, b1, ai);
  hipLaunchKernelGGL(k_mlp2ln,  dim3(512),  dim3(512), 0, stream, ai, w2t, b2, x, l2g, l2b, out);
}

// Round 18
// 228.019 us; speedup vs baseline: 1.4195x; 1.0156x over previous
//
#include <hip/hip_runtime.h>
#include <hip/hip_bf16.h>

#define DIMD 384
#define SEQL 4096
#define NBATCH 8
#define NTOK (NBATCH*SEQL)

typedef float f32x4 __attribute__((ext_vector_type(4)));
typedef short s16x8 __attribute__((ext_vector_type(8)));
typedef unsigned short u16;
typedef __hip_bfloat16 bf16;

__device__ __forceinline__ float sigf(float x){ return 1.f/(1.f+__expf(-x)); }

// async global->LDS, 16B per lane. LDS dest must be wave-uniform base + lane*16.
typedef __attribute__((address_space(3))) void lds_void;
typedef const __attribute__((address_space(1))) void glb_void;
__device__ __forceinline__ void gl_lds16(const void* g, void* l) {
  __builtin_amdgcn_global_load_lds((glb_void*)g, (lds_void*)l, 16, 0, 0);
}

// ---------------- workspace layout (bytes) ----------------
#define OFF_LAM   0ul
#define OFF_WQ    4096ul                       // bf16 [1536][384]
#define OFF_CW    (OFF_WQ + 1179648ul)         // bf16 [384][448]
#define OFF_W1T   (OFF_CW + 344064ul)          // bf16 [768][384]
#define OFF_W2T   (OFF_W1T + 589824ul)         // bf16 [384][768]
#define OFF_XC    4194304ul                    // bf16 [32768][384]
#define OFF_Q     (OFF_XC + 25165824ul)        // bf16 [32768][384]
#define OFF_U     (OFF_XC + 50331648ul)        // bf16 [32768][384]
#define OFF_AI    OFF_U                        // bf16 [32768][768] (reuse after u dead)
#define OFF_H     (OFF_U + 50331648ul)         // bf16 [32768][384]
// total = 130,023,424 bytes

// ---------------- prep: weight transposes to [n][k] bf16 ----------------
__global__ void k_prep_w(const float* __restrict__ qw, const float* __restrict__ kw,
                         const float* __restrict__ vw, const float* __restrict__ gw,
                         const float* __restrict__ cw, const float* __restrict__ w1,
                         const float* __restrict__ w2,
                         bf16* __restrict__ wqt, bf16* __restrict__ cwt,
                         bf16* __restrict__ w1t, bf16* __restrict__ w2t) {
  const int total = 589824 + 172032 + 294912 + 294912;
  for (int j = blockIdx.x*blockDim.x + threadIdx.x; j < total; j += gridDim.x*blockDim.x) {
    if (j < 589824) {
      int n = j / 384, k = j % 384;
      int mat = n / 384;
      int np = n % 384;                        // (384 not pow2 -> %, not &)
      const float* W = (mat==0)?qw:(mat==1)?kw:(mat==2)?vw:gw;
      wqt[(size_t)n*384 + k] = __float2bfloat16(W[(size_t)k*384 + np]);
    } else if (j < 589824 + 172032) {
      int jj = j - 589824;
      int o = jj / 448, k = jj % 448;
      int kap = k >> 6, i = k & 63;
      cwt[(size_t)o*448 + k] = __float2bfloat16(cw[((size_t)o*64 + i)*7 + kap]);
    } else if (j < 589824 + 172032 + 294912) {
      int jj = j - (589824 + 172032);
      int n = jj / 384, k = jj % 384;
      w1t[(size_t)n*384 + k] = __float2bfloat16(w1[(size_t)k*768 + n]);
    } else {
      int jj = j - (589824 + 172032 + 294912);
      int n = jj / 768, k = jj % 768;
      w2t[(size_t)n*768 + k] = __float2bfloat16(w2[(size_t)k*384 + n]);
    }
  }
}

__global__ void k_prep_lam(const float* __restrict__ decay, float* __restrict__ lam) {
  __shared__ float red[6];
  int t = threadIdx.x; // 384 threads
  float v = sigf(decay[t]);
  for (int off = 32; off; off >>= 1) v += __shfl_xor(v, off, 64);
  if ((t & 63) == 0) red[t >> 6] = v;
  __syncthreads();
  if (t == 0) {
    float s = 0.f;
    for (int i = 0; i < 6; ++i) s += red[i];
    lam[0] = s * (1.f/384.f);
  }
}

// ---------------- grouped conv (k=7, groups=6) + silu -> xc bf16 ----------------
__global__ __launch_bounds__(256) void k_conv(const float* __restrict__ x, const float* __restrict__ cb,
                                              const bf16* __restrict__ cwt, bf16* __restrict__ xc) {
  int id = blockIdx.x;             // 1536 = 8 b * 32 st * 6 g
  int g = id % 6, st = (id/6) & 31, b = id / 192;
  int s0 = st * 128;
  __shared__ u16 xls[134*72];
  __shared__ u16 wls[64*456];
  int tid = threadIdx.x;
  for (int r0 = 0; r0 < 144; r0 += 16) {
    int row = r0 + (tid >> 4);
    if (row < 134) {
      int col = (tid & 15) * 4;
      int s = s0 - 3 + row;
      float4 v = make_float4(0.f,0.f,0.f,0.f);
      if (s >= 0 && s < SEQL)
        v = *reinterpret_cast<const float4*>(x + ((size_t)(b*SEQL + s))*DIMD + g*64 + col);
      u16* dst = &xls[row*72 + col];
      bf16 t0 = __float2bfloat16(v.x); dst[0] = *reinterpret_cast<u16*>(&t0);
      bf16 t1 = __float2bfloat16(v.y); dst[1] = *reinterpret_cast<u16*>(&t1);
      bf16 t2 = __float2bfloat16(v.z); dst[2] = *reinterpret_cast<u16*>(&t2);
      bf16 t3 = __float2bfloat16(v.w); dst[3] = *reinterpret_cast<u16*>(&t3);
    }
  }
  for (int i0 = 0; i0 < 28672; i0 += 1024) {
    int i = i0 + tid*4;
    int o = i / 448, k = i % 448;
    *reinterpret_cast<uint2*>(&wls[o*456 + k]) =
      *reinterpret_cast<const uint2*>(cwt + ((size_t)(g*64 + o))*448 + k);
  }
  __syncthreads();
  int w = tid >> 6, l = tid & 63, l15 = l & 15, lh = l >> 4;
  f32x4 zz = {0.f,0.f,0.f,0.f};
  f32x4 acc[2][4];
  for (int i=0;i<2;++i) for (int jn=0;jn<4;++jn) acc[i][jn]=zz;
  for (int kap = 0; kap < 7; ++kap) {
#pragma unroll
    for (int ic = 0; ic < 2; ++ic) {
      s16x8 a0 = *reinterpret_cast<const s16x8*>(&xls[(w*32 +  0 + l15 + kap)*72 + ic*32 + lh*8]);
      s16x8 a1 = *reinterpret_cast<const s16x8*>(&xls[(w*32 + 16 + l15 + kap)*72 + ic*32 + lh*8]);
#pragma unroll
      for (int nf = 0; nf < 4; ++nf) {
        s16x8 bfr = *reinterpret_cast<const s16x8*>(&wls[(nf*16 + l15)*456 + kap*64 + ic*32 + lh*8]);
        acc[0][nf] = __builtin_amdgcn_mfma_f32_16x16x32_bf16(a0, bfr, acc[0][nf], 0,0,0);
        acc[1][nf] = __builtin_amdgcn_mfma_f32_16x16x32_bf16(a1, bfr, acc[1][nf], 0,0,0);
      }
    }
  }
#pragma unroll
  for (int nf = 0; nf < 4; ++nf) {
    int ch = g*64 + nf*16 + l15;
    float bias = cb[ch];
#pragma unroll
    for (int mf = 0; mf < 2; ++mf) {
#pragma unroll
      for (int r = 0; r < 4; ++r) {
        int m = w*32 + mf*16 + lh*4 + r;
        float v = acc[mf][nf][r] + bias;
        v = v * sigf(v);
        xc[((size_t)(b*SEQL + s0 + m))*DIMD + ch] = __float2bfloat16(v);
      }
    }
  }
}

// ---------------- fused QKVG GEMM (R17): 8 waves, wave owns (matrix, 16-col half) ------------
__global__ __launch_bounds__(512) void k_qkvg(const bf16* __restrict__ xc, const bf16* __restrict__ wt,
    const float* __restrict__ qb, const float* __restrict__ kb,
    const float* __restrict__ vb, const float* __restrict__ gb,
    bf16* __restrict__ qout, bf16* __restrict__ uout) {
  int raw = blockIdx.x;                       // 3072
  int vv = (raw & 7)*384 + (raw >> 3);        // XCD swizzle
  int mt = vv / 12, ct = vv % 12;
  int m0 = mt*128, c0 = ct*32;
  __shared__ __align__(16) u16 smem[16384];   // 32KB dbuf 2x[128][64] / exchange overlay
  int tid = threadIdx.x, w = tid >> 6, l = tid & 63, l15 = l & 15, lh = l >> 4;
  int mat = w >> 1, ch0 = (w & 1)*16;         // wave's matrix + col-half
  f32x4 zz = {0.f,0.f,0.f,0.f};
  f32x4 acc[8];
#pragma unroll
  for (int i=0;i<8;++i) acc[i]=zz;
  const bf16* bp = wt + ((size_t)(mat*384 + c0 + ch0 + l15))*384 + lh*8;
  s16x8 bc0 = *reinterpret_cast<const s16x8*>(bp);
  s16x8 bc1 = *reinterpret_cast<const s16x8*>(bp + 32);
  s16x8 bn0, bn1;
#pragma unroll
  for (int p = 0; p < 2; ++p) {
    int off16 = p*512 + tid;
    int row = off16 >> 3, slot = off16 & 7;
    int ss = slot ^ (row & 7);
    gl_lds16(xc + ((size_t)(m0+row))*DIMD + ss*8, (char*)smem + off16*16);
  }
  __syncthreads();
  for (int kc = 0; kc < 6; ++kc) {
    const u16* cur = smem + (kc & 1)*8192;
    if (kc < 5) {
      char* nxt = (char*)(smem + ((kc & 1)^1)*8192);
#pragma unroll
      for (int p = 0; p < 2; ++p) {
        int off16 = p*512 + tid;
        int row = off16 >> 3, slot = off16 & 7;
        int ss = slot ^ (row & 7);
        gl_lds16(xc + ((size_t)(m0+row))*DIMD + (kc+1)*64 + ss*8, nxt + off16*16);
      }
      int nb = (kc+1)*64;
      bn0 = *reinterpret_cast<const s16x8*>(bp + nb);
      bn1 = *reinterpret_cast<const s16x8*>(bp + nb + 32);
    }
#pragma unroll
    for (int kk = 0; kk < 2; ++kk) {
      s16x8 curb = kk ? bc1 : bc0;
#pragma unroll
      for (int mf = 0; mf < 8; ++mf) {
        s16x8 af = *reinterpret_cast<const s16x8*>(
            &cur[(mf*16 + l15)*64 + (((kk*4 + lh) ^ (l15 & 7))*8)]);
        acc[mf] = __builtin_amdgcn_mfma_f32_16x16x32_bf16(af, curb, acc[mf], 0,0,0);
      }
    }
    __syncthreads();
    bc0 = bn0; bc1 = bn1;
  }
  const float* bpv = (mat==0)?qb:(mat==1)?kb:(mat==2)?vb:gb;
  float bias = bpv[c0 + ch0 + l15];
  if (mat == 0) {
#pragma unroll
    for (int mf=0;mf<8;++mf)
#pragma unroll
      for (int r=0;r<4;++r) {
        int m = mf*16 + lh*4 + r, c = ch0 + l15;
        qout[((size_t)(m0+m))*DIMD + c0 + c] = __float2bfloat16(acc[mf][r] + bias);
      }
  } else {
    u16* exm = smem + (size_t)(mat-1)*(128*40);
#pragma unroll
    for (int mf=0;mf<8;++mf)
#pragma unroll
      for (int r=0;r<4;++r) {
        int m = mf*16 + lh*4 + r, c = ch0 + l15;
        bf16 t = __float2bfloat16(acc[mf][r] + bias);
        exm[m*40 + c] = *reinterpret_cast<u16*>(&t);
      }
  }
  __syncthreads();
#pragma unroll
  for (int p = 0; p < 8; ++p) {
    int idx = p*512 + tid;
    int m = idx >> 5, c = idx & 31;
    u16 kr = smem[0*(128*40) + m*40 + c];
    u16 vr = smem[1*(128*40) + m*40 + c];
    u16 gr = smem[2*(128*40) + m*40 + c];
    float kvv = __bfloat162float(*reinterpret_cast<bf16*>(&kr));
    float vvv = __bfloat162float(*reinterpret_cast<bf16*>(&vr));
    float gvv = __bfloat162float(*reinterpret_cast<bf16*>(&gr));
    uout[((size_t)(m0+m))*DIMD + c0 + c] = __float2bfloat16(vvv * sigf(gvv) * kvv);
  }
}

// ---------------- decayed cumsum + q*diag + LN1 -> h bf16 (48KB LDS, 3 blocks/CU) -------------
__global__ __launch_bounds__(384) void k_scan(const bf16* __restrict__ u, const bf16* __restrict__ q,
    const float* __restrict__ lam_p, const float* __restrict__ l1g, const float* __restrict__ l1b,
    bf16* __restrict__ h) {
  int b = blockIdx.x >> 5, c = blockIdx.x & 31; // 8 x 32
  int d = threadIdx.x;                          // 384
  float lam = lam_p[0];
  __shared__ float ols[32*384];                 // 48 KB
  __shared__ float lgs[384], lbs[384];
  lgs[d] = l1g[d]; lbs[d] = l1b[d];
  int s0 = c*128;
  size_t base = ((size_t)b*SEQL)*DIMD + d;
  float carry = 0.f;
  int sstart = s0 - 64; if (sstart < 0) sstart = 0;
  for (int s = sstart; s < s0; s += 8) {
    float uv[8];
#pragma unroll
    for (int j = 0; j < 8; ++j) uv[j] = __bfloat162float(u[base + (size_t)(s+j)*DIMD]);
#pragma unroll
    for (int j = 0; j < 8; ++j) carry = carry*lam + uv[j];
  }
  int w = d >> 6, lane = d & 63;
  for (int p = 0; p < 4; ++p) {
    int sb = s0 + p*32;
    __syncthreads();
    for (int it0 = 0; it0 < 32; it0 += 8) {
      float uv[8], qv[8];
#pragma unroll
      for (int j = 0; j < 8; ++j) uv[j] = __bfloat162float(u[base + (size_t)(sb+it0+j)*DIMD]);
#pragma unroll
      for (int j = 0; j < 8; ++j) qv[j] = __bfloat162float(q[base + (size_t)(sb+it0+j)*DIMD]);
#pragma unroll
      for (int j = 0; j < 8; ++j) {
        carry = carry*lam + uv[j];
        ols[(it0+j)*384 + d] = carry * qv[j];
      }
    }
    __syncthreads();
    for (int t = w; t < 32; t += 6) {
      float vv[6]; float s1 = 0.f, s2 = 0.f;
#pragma unroll
      for (int j = 0; j < 6; ++j) {
        vv[j] = ols[t*384 + j*64 + lane];
        s1 += vv[j]; s2 += vv[j]*vv[j];
      }
      for (int off = 32; off; off >>= 1) { s1 += __shfl_xor(s1, off, 64); s2 += __shfl_xor(s2, off, 64); }
      float mean = s1 * (1.f/384.f);
      float var = s2 * (1.f/384.f) - mean*mean;
      float rs = rsqrtf(var + 1e-5f);
      size_t rowo = ((size_t)(b*SEQL + sb + t))*DIMD;
#pragma unroll
      for (int j = 0; j < 6; ++j) {
        int dd = j*64 + lane;
        h[rowo + dd] = __float2bfloat16((vv[j]-mean)*rs*lgs[dd] + lbs[dd]);
      }
    }
  }
}

// ---------------- MLP GEMM1 + silu -> ai bf16 (T3 stage-ahead dbuf, BK=64) --------------
__global__ __launch_bounds__(512) void k_mlp1(const bf16* __restrict__ h, const bf16* __restrict__ w1t,
                                              const float* __restrict__ b1, bf16* __restrict__ ai) {
  int raw = blockIdx.x;                 // 1536
  int vv = (raw & 7)*192 + (raw >> 3);
  int mt = vv / 6, nt = vv % 6;
  int m0 = mt*128, n0 = nt*128;
  __shared__ __align__(16) u16 als[16384];   // 32KB = 2 x [128][64]
  int tid = threadIdx.x, w = tid >> 6, l = tid & 63, l15 = l & 15, lh = l >> 4;
  int wm = (w >> 2)*64, wn = (w & 3)*32;
  f32x4 zz = {0.f,0.f,0.f,0.f};
  f32x4 acc[4][2];
#pragma unroll
  for (int i=0;i<4;++i) for (int jn=0;jn<2;++jn) acc[i][jn]=zz;
  const bf16* bp0 = w1t + ((size_t)(n0 + wn + l15))*384 + lh*8;
  s16x8 bA[2], bB[2];
#pragma unroll
  for (int nf = 0; nf < 2; ++nf)
    bA[nf] = *reinterpret_cast<const s16x8*>(bp0 + (size_t)nf*16*384);
#pragma unroll
  for (int p = 0; p < 2; ++p) {
    int off16 = p*512 + tid;
    int row = off16 >> 3, slot = off16 & 7;
    int ss = slot ^ (row & 7);
    gl_lds16(h + ((size_t)(m0+row))*DIMD + ss*8, (char*)als + off16*16);
  }
  __syncthreads();
  for (int kc = 0; kc < 6; ++kc) {
    const u16* cur = als + (kc & 1)*8192;
    if (kc < 5) {
      char* nxt = (char*)(als + ((kc & 1)^1)*8192);
#pragma unroll
      for (int p = 0; p < 2; ++p) {
        int off16 = p*512 + tid;
        int row = off16 >> 3, slot = off16 & 7;
        int ss = slot ^ (row & 7);
        gl_lds16(h + ((size_t)(m0+row))*DIMD + (kc+1)*64 + ss*8, nxt + off16*16);
      }
    }
#pragma unroll
    for (int kk = 0; kk < 2; ++kk) {
      int nko = (kk == 0) ? (kc*64 + 32) : ((kc < 5) ? (kc+1)*64 : -1);
      if (nko >= 0) {
        if (kk) {
#pragma unroll
          for (int nf = 0; nf < 2; ++nf)
            bA[nf] = *reinterpret_cast<const s16x8*>(bp0 + (size_t)nf*16*384 + nko);
        } else {
#pragma unroll
          for (int nf = 0; nf < 2; ++nf)
            bB[nf] = *reinterpret_cast<const s16x8*>(bp0 + (size_t)nf*16*384 + nko);
        }
      }
#pragma unroll
      for (int mf = 0; mf < 4; ++mf) {
        s16x8 af = *reinterpret_cast<const s16x8*>(
            &cur[(wm + mf*16 + l15)*64 + (((kk*4 + lh) ^ (l15 & 7))*8)]);
#pragma unroll
        for (int nf = 0; nf < 2; ++nf)
          acc[mf][nf] = __builtin_amdgcn_mfma_f32_16x16x32_bf16(
              af, kk ? bB[nf] : bA[nf], acc[mf][nf], 0,0,0);
      }
    }
    __syncthreads();
  }
  float bias[2];
#pragma unroll
  for (int nf = 0; nf < 2; ++nf) bias[nf] = b1[n0 + wn + nf*16 + l15];
#pragma unroll
  for (int mf = 0; mf < 4; ++mf)
#pragma unroll
    for (int nf = 0; nf < 2; ++nf)
#pragma unroll
      for (int r = 0; r < 4; ++r) {
        int m = wm + mf*16 + lh*4 + r, ch = n0 + wn + nf*16 + l15;
        float v = acc[mf][nf][r] + bias[nf];
        v = v * sigf(v);
        ai[(size_t)(m0+m)*768 + ch] = __float2bfloat16(v);
      }
}

// ---------------- fused MLP GEMM2 + bias + residual + LN2 -> out f32 (R18: x issue-early) -----
// 512 threads (8 waves), M=64/block, grid 512. Wave w owns cols [w*48, w*48+48).
// x residual prefetched into 48 regs right after the prologue barrier (T14): loads drain at
// kc=0's barrier, hidden under a full compute phase, removing the serial epilogue x-tail.
__global__ __launch_bounds__(512) void k_mlp2ln(const bf16* __restrict__ ai, const bf16* __restrict__ w2t,
                                                const float* __restrict__ b2, const float* __restrict__ x,
                                                const float* __restrict__ l2g, const float* __restrict__ l2b,
                                                float* __restrict__ out) {
  int raw = blockIdx.x;                 // 512
  int mt = (raw & 7)*64 + (raw >> 3);   // XCD swizzle
  int m0 = mt*64;
  __shared__ __align__(16) u16 als[16384];    // 32KB = 2 x [64][128]
  __shared__ float pls[8][64][2];             // per-wave row partials (4KB)
  int tid = threadIdx.x, w = tid >> 6, l = tid & 63, l15 = l & 15, lh = l >> 4;
  int wn = w*48;
  f32x4 zz = {0.f,0.f,0.f,0.f};
  f32x4 acc[4][3];
#pragma unroll
  for (int i=0;i<4;++i)
#pragma unroll
    for (int jn=0;jn<3;++jn) acc[i][jn]=zz;
  const bf16* bp0 = w2t + ((size_t)(wn + l15))*768 + lh*8;
  s16x8 bA[3], bB[3];
#pragma unroll
  for (int nf = 0; nf < 3; ++nf)
    bA[nf] = *reinterpret_cast<const s16x8*>(bp0 + (size_t)nf*16*768);
  // prologue: tile 0 -> buf0
#pragma unroll
  for (int p = 0; p < 2; ++p) {
    int off16 = p*512 + tid;
    int row = off16 >> 4, slot = off16 & 15;
    int ss = slot ^ (row & 7);
    gl_lds16(ai + ((size_t)(m0+row))*768 + ss*8, (char*)als + off16*16);
  }
  __syncthreads();
  // x issue-early: 48 scattered f32 loads; drained by kc=0's end barrier (full phase of cover)
  float xpre[4][4][3];
#pragma unroll
  for (int mf = 0; mf < 4; ++mf)
#pragma unroll
    for (int r = 0; r < 4; ++r) {
      int m = mf*16 + lh*4 + r;
      const float* xr = x + (size_t)(m0+m)*DIMD + wn + l15;
#pragma unroll
      for (int nf = 0; nf < 3; ++nf) xpre[mf][r][nf] = xr[nf*16];
    }
  for (int kc = 0; kc < 6; ++kc) {
    const u16* cur = als + (kc & 1)*8192;
    if (kc < 5) {
      char* nxt = (char*)(als + ((kc & 1)^1)*8192);
#pragma unroll
      for (int p = 0; p < 2; ++p) {
        int off16 = p*512 + tid;
        int row = off16 >> 4, slot = off16 & 15;
        int ss = slot ^ (row & 7);
        gl_lds16(ai + ((size_t)(m0+row))*768 + (kc+1)*128 + ss*8, nxt + off16*16);
      }
    }
#pragma unroll
    for (int kk = 0; kk < 4; ++kk) {
      int nko = (kk < 3) ? (kc*128 + (kk+1)*32) : ((kc < 5) ? (kc+1)*128 : -1);
      if (nko >= 0) {
        if (kk & 1) {
#pragma unroll
          for (int nf = 0; nf < 3; ++nf)
            bA[nf] = *reinterpret_cast<const s16x8*>(bp0 + (size_t)nf*16*768 + nko);
        } else {
#pragma unroll
          for (int nf = 0; nf < 3; ++nf)
            bB[nf] = *reinterpret_cast<const s16x8*>(bp0 + (size_t)nf*16*768 + nko);
        }
      }
#pragma unroll
      for (int mf = 0; mf < 4; ++mf) {
        s16x8 af = *reinterpret_cast<const s16x8*>(
            &cur[(mf*16 + l15)*128 + (((kk*4 + lh) ^ (l15 & 7))*8)]);
#pragma unroll
        for (int nf = 0; nf < 3; ++nf)
          acc[mf][nf] = __builtin_amdgcn_mfma_f32_16x16x32_bf16(
              af, (kk & 1) ? bB[nf] : bA[nf], acc[mf][nf], 0,0,0);
      }
    }
    __syncthreads();
  }
  // epilogue: v = acc + b2 + xpre (in regs), row stats, LN, store
  float bias[3];
#pragma unroll
  for (int nf = 0; nf < 3; ++nf) bias[nf] = b2[wn + nf*16 + l15];
#pragma unroll
  for (int mf = 0; mf < 4; ++mf) {
#pragma unroll
    for (int r = 0; r < 4; ++r) {
      int m = mf*16 + lh*4 + r;
      float sa = 0.f, sb = 0.f;
#pragma unroll
      for (int nf = 0; nf < 3; ++nf) {
        float v = acc[mf][nf][r] + bias[nf] + xpre[mf][r][nf];
        acc[mf][nf][r] = v;
        sa += v; sb += v*v;
      }
#pragma unroll
      for (int off = 1; off < 16; off <<= 1) {
        sa += __shfl_xor(sa, off, 16);
        sb += __shfl_xor(sb, off, 16);
      }
      if (l15 == 0) { pls[w][m][0] = sa; pls[w][m][1] = sb; }
    }
  }
  __syncthreads();
  float lg[3], lb[3];
#pragma unroll
  for (int nf = 0; nf < 3; ++nf) { lg[nf] = l2g[wn + nf*16 + l15]; lb[nf] = l2b[wn + nf*16 + l15]; }
#pragma unroll
  for (int mf = 0; mf < 4; ++mf) {
#pragma unroll
    for (int r = 0; r < 4; ++r) {
      int m = mf*16 + lh*4 + r;
      float S1 = 0.f, S2 = 0.f;
#pragma unroll
      for (int ww = 0; ww < 8; ++ww) { S1 += pls[ww][m][0]; S2 += pls[ww][m][1]; }
      float mean = S1 * (1.f/384.f);
      float var = S2 * (1.f/384.f) - mean*mean;
      float rs = rsqrtf(var + 1e-5f);
      float* orow = out + (size_t)(m0+m)*DIMD + wn + l15;
#pragma unroll
      for (int nf = 0; nf < 3; ++nf)
        orow[nf*16] = (acc[mf][nf][r] - mean)*rs*lg[nf] + lb[nf];
    }
  }
}

extern "C" void kernel_launch(void* const* d_in, const int* in_sizes, int n_in,
                              void* d_out, int out_size, void* d_ws, size_t ws_size,
                              hipStream_t stream) {
  const float* x   = (const float*)d_in[0];
  const float* cw  = (const float*)d_in[1];
  const float* cb  = (const float*)d_in[2];
  const float* qw  = (const float*)d_in[3];
  const float* qb  = (const float*)d_in[4];
  const float* kw  = (const float*)d_in[5];
  const float* kb  = (const float*)d_in[6];
  const float* vw  = (const float*)d_in[7];
  const float* vb  = (const float*)d_in[8];
  const float* gw  = (const float*)d_in[9];
  const float* gb  = (const float*)d_in[10];
  const float* dec = (const float*)d_in[11];
  const float* l1g = (const float*)d_in[12];
  const float* l1b = (const float*)d_in[13];
  const float* w1  = (const float*)d_in[14];
  const float* b1  = (const float*)d_in[15];
  const float* w2  = (const float*)d_in[16];
  const float* b2  = (const float*)d_in[17];
  const float* l2g = (const float*)d_in[18];
  const float* l2b = (const float*)d_in[19];

  char* ws = (char*)d_ws;
  float* lam = (float*)(ws + OFF_LAM);
  bf16* wqt  = (bf16*)(ws + OFF_WQ);
  bf16* cwt  = (bf16*)(ws + OFF_CW);
  bf16* w1t  = (bf16*)(ws + OFF_W1T);
  bf16* w2t  = (bf16*)(ws + OFF_W2T);
  bf16* xc   = (bf16*)(ws + OFF_XC);
  bf16* q    = (bf16*)(ws + OFF_Q);
  bf16* u    = (bf16*)(ws + OFF_U);
  bf16* hbuf = (bf16*)(ws + OFF_H);
  bf16* ai   = (bf16*)(ws + OFF_AI);
  float* out = (float*)d_out;

  hipLaunchKernelGGL(k_prep_w,  dim3(1024), dim3(256), 0, stream, qw,kw,vw,gw,cw,w1,w2, wqt,cwt,w1t,w2t);
  hipLaunchKernelGGL(k_prep_lam,dim3(1),    dim3(384), 0, stream, dec, lam);
  hipLaunchKernelGGL(k_conv,    dim3(1536), dim3(256), 0, stream, x, cb, cwt, xc);
  hipLaunchKernelGGL(k_qkvg,    dim3(3072), dim3(512), 0, stream, xc, wqt, qb,kb,vb,gb, q, u);
  hipLaunchKernelGGL(k_scan,    dim3(256),  dim3(384), 0, stream, u, q, lam, l1g, l1b, hbuf);
  hipLaunchKernelGGL(k_mlp1,    dim3(1536), dim3(512), 0, stream, hbuf, w1t, b1, ai);
  hipLaunchKernelGGL(k_mlp2ln,  dim3(512),  dim3(512), 0, stream, ai, w2t, b2, x, l2g, l2b, out);
}